// Round 1
// baseline (683.539 us; speedup 1.0000x reference)
//
#include <hip/hip_runtime.h>
#include <hip/hip_bf16.h>
#include <math.h>

#define R_N 8192
#define D_K 4096
#define C_N 80
#define NC2 160          // both heads concatenated
#define KSPLIT 8
#define KSLICE (D_K / KSPLIT)   // 512
#define BK 32
#define BM 128
#define KPRE 512
#define TOPK 100
#define LIST_CAP (80 * 512)

// ---------------------------------------------------------------------------
// zero d_out + counter
// ---------------------------------------------------------------------------
__global__ __launch_bounds__(256) void zero_kernel(float* __restrict__ out, unsigned* __restrict__ cnt) {
    int idx = blockIdx.x * 256 + threadIdx.x;
    if (idx < R_N * C_N) out[idx] = 0.0f;
    if (blockIdx.x == 0 && threadIdx.x == 0) *cnt = 0u;
}

// ---------------------------------------------------------------------------
// fused dual GEMM (fp32), K-split into partials
// grid: 512 blocks = 64 row-blocks x 8 K-slices; 256 threads
// thread tile: 8 rows x 10 cols; rg = tid>>4 (16 groups of 8 rows = 128 rows),
// cg = tid&15 (16 groups of 10 cols = 160 cols)
// ---------------------------------------------------------------------------
__global__ __launch_bounds__(256) void gemm_part(const float* __restrict__ x,
                                                 const float* __restrict__ Wc,
                                                 const float* __restrict__ Wd,
                                                 float* __restrict__ part) {
    __shared__ float xs[BK][BM + 4];   // [k][row], pad 132 keeps b128 16B-aligned
    __shared__ float ws[BK][NC2 + 4];  // [k][col], pad 164 keeps float4 16B-aligned

    const int b   = blockIdx.x;
    const int rb  = b & 63;
    const int ks  = b >> 6;
    const int row0 = rb * BM;
    const int kbase = ks * KSLICE;
    const int tid = threadIdx.x;
    const int rg = tid >> 4, cg = tid & 15;
    const int r0 = rg * 8, c0 = cg * 10;

    float acc[8][10];
#pragma unroll
    for (int i = 0; i < 8; ++i)
#pragma unroll
        for (int j = 0; j < 10; ++j) acc[i][j] = 0.0f;

    for (int ch = 0; ch < KSLICE / BK; ++ch) {
        const int k0 = kbase + ch * BK;
        // stage x tile (transposed into [k][row])
#pragma unroll
        for (int i = 0; i < 4; ++i) {
            int li = tid + 256 * i;
            int r = li >> 3, v = li & 7;
            float4 t4 = *(const float4*)(x + (size_t)(row0 + r) * D_K + k0 + v * 4);
            int kk = v * 4;
            xs[kk + 0][r] = t4.x; xs[kk + 1][r] = t4.y;
            xs[kk + 2][r] = t4.z; xs[kk + 3][r] = t4.w;
        }
        // stage W tile: cols 0..79 = Wc, 80..159 = Wd
#pragma unroll
        for (int i = 0; i < 5; ++i) {
            int li = tid + 256 * i;
            int kk = li / 40, q = li % 40;
            const float* src = (q < 20) ? (Wc + (size_t)(k0 + kk) * C_N + q * 4)
                                        : (Wd + (size_t)(k0 + kk) * C_N + (q - 20) * 4);
            float4 t4 = *(const float4*)src;
            int cc = (q < 20) ? q * 4 : C_N + (q - 20) * 4;
            *(float4*)&ws[kk][cc] = t4;
        }
        __syncthreads();
#pragma unroll 4
        for (int kk = 0; kk < BK; ++kk) {
            float4 xa = *(const float4*)&xs[kk][r0];
            float4 xb = *(const float4*)&xs[kk][r0 + 4];
            float a[8] = {xa.x, xa.y, xa.z, xa.w, xb.x, xb.y, xb.z, xb.w};
            float w[10];
#pragma unroll
            for (int j = 0; j < 5; ++j) {
                float2 w2 = *(const float2*)&ws[kk][c0 + 2 * j];
                w[2 * j] = w2.x; w[2 * j + 1] = w2.y;
            }
#pragma unroll
            for (int rr = 0; rr < 8; ++rr)
#pragma unroll
                for (int j = 0; j < 10; ++j)
                    acc[rr][j] = fmaf(a[rr], w[j], acc[rr][j]);
        }
        __syncthreads();
    }
    // write partial [ks][row][col]
#pragma unroll
    for (int rr = 0; rr < 8; ++rr) {
        size_t base = ((size_t)ks * R_N + row0 + r0 + rr) * NC2 + c0;
#pragma unroll
        for (int j = 0; j < 5; ++j)
            *(float2*)(part + base + 2 * j) = make_float2(acc[rr][2 * j], acc[rr][2 * j + 1]);
    }
}

// ---------------------------------------------------------------------------
// reduce K-split partials (pairwise tree, deterministic), add bias, route:
// cols 0..79 -> cls [R,80]; cols 80..159 -> detT [80, R] (transposed)
// ---------------------------------------------------------------------------
__global__ __launch_bounds__(256) void reduce_bias(const float* __restrict__ part,
                                                   const float* __restrict__ bc,
                                                   const float* __restrict__ bd,
                                                   float* __restrict__ cls,
                                                   float* __restrict__ detT) {
    const size_t STRIDE = (size_t)R_N * NC2;
    size_t idx = (size_t)blockIdx.x * 256 + threadIdx.x;
    int row = (int)(idx / NC2), col = (int)(idx % NC2);
    float p0 = part[idx + 0 * STRIDE], p1 = part[idx + 1 * STRIDE];
    float p2 = part[idx + 2 * STRIDE], p3 = part[idx + 3 * STRIDE];
    float p4 = part[idx + 4 * STRIDE], p5 = part[idx + 5 * STRIDE];
    float p6 = part[idx + 6 * STRIDE], p7 = part[idx + 7 * STRIDE];
    float s = ((p0 + p1) + (p2 + p3)) + ((p4 + p5) + (p6 + p7));
    if (col < C_N) {
        cls[(size_t)row * C_N + col] = s + bc[col];
    } else {
        detT[(size_t)(col - C_N) * R_N + row] = s + bd[col - C_N];
    }
}

// ---------------------------------------------------------------------------
// softmax over classes (axis=1); writes result transposed into P [C][R]
// one wave per row
// ---------------------------------------------------------------------------
__global__ __launch_bounds__(256) void row_softmax(const float* __restrict__ cls,
                                                   float* __restrict__ P) {
    int tid = threadIdx.x;
    int wave = tid >> 6, lane = tid & 63;
    int row = blockIdx.x * 4 + wave;
    float v0 = cls[(size_t)row * C_N + lane];
    float v1 = (lane < 16) ? cls[(size_t)row * C_N + 64 + lane] : -INFINITY;
    float m = fmaxf(v0, v1);
#pragma unroll
    for (int off = 32; off > 0; off >>= 1) m = fmaxf(m, __shfl_xor(m, off, 64));
    float e0 = expf(v0 - m);
    float e1 = (lane < 16) ? expf(v1 - m) : 0.0f;
    float s = e0 + e1;
#pragma unroll
    for (int off = 32; off > 0; off >>= 1) s += __shfl_xor(s, off, 64);
    P[(size_t)lane * R_N + row] = e0 / s;
    if (lane < 16) P[(size_t)(64 + lane) * R_N + row] = e1 / s;
}

// ---------------------------------------------------------------------------
// softmax over proposals (axis=0) per class, multiplied into P
// one block per class
// ---------------------------------------------------------------------------
__global__ __launch_bounds__(256) void col_softmax_mul(const float* __restrict__ detT,
                                                       float* __restrict__ P) {
    __shared__ float red[256];
    int c = blockIdx.x, tid = threadIdx.x;
    const float* dc = detT + (size_t)c * R_N;
    float m = -INFINITY;
    for (int r = tid; r < R_N; r += 256) m = fmaxf(m, dc[r]);
    red[tid] = m; __syncthreads();
    for (int s2 = 128; s2 > 0; s2 >>= 1) {
        if (tid < s2) red[tid] = fmaxf(red[tid], red[tid + s2]);
        __syncthreads();
    }
    m = red[0]; __syncthreads();
    float sum = 0.0f;
    for (int r = tid; r < R_N; r += 256) sum += expf(dc[r] - m);
    red[tid] = sum; __syncthreads();
    for (int s2 = 128; s2 > 0; s2 >>= 1) {
        if (tid < s2) red[tid] += red[tid + s2];
        __syncthreads();
    }
    float s = red[0];
    float* pc = P + (size_t)c * R_N;
    for (int r = tid; r < R_N; r += 256) pc[r] = pc[r] * (expf(dc[r] - m) / s);
}

// ---------------------------------------------------------------------------
// per-class: top-512 (exact jax.lax.top_k semantics), IoU mask, greedy NMS,
// append kept (score, flat pos) to global list. one block per class.
// ---------------------------------------------------------------------------
__global__ __launch_bounds__(256) void nms_kernel(const float* __restrict__ P,
                                                  const float* __restrict__ boxes,
                                                  float* __restrict__ g_ls,
                                                  unsigned* __restrict__ g_lp,
                                                  unsigned* __restrict__ g_cnt) {
    __shared__ unsigned long long skeys[1024];
    __shared__ unsigned long long msk[512][8];
    __shared__ unsigned hist[256];
    __shared__ unsigned sh_prefix, sh_k, sh_cnt;
    __shared__ float bx1[512], by1[512], bx2[512], by2[512], barea[512], svals[512];
    __shared__ int sridx[512], svalid[512], skeep[512];

    const int c = blockIdx.x, tid = threadIdx.x;
    const float* pc = P + (size_t)c * R_N;

    // ---- radix-select 512th-largest score (exact bit pattern) ----
    if (tid == 0) { sh_prefix = 0u; sh_k = KPRE; }
    __syncthreads();
    for (int b = 3; b >= 0; --b) {
        hist[tid] = 0;
        if (tid < 0) {} // (256 threads == 256 bins)
        __syncthreads();
        unsigned pfx = sh_prefix;
        for (int i = 0; i < 32; ++i) {
            int r = tid + 256 * i;
            unsigned u = __float_as_uint(pc[r]);
            bool ok = (b == 3) || ((u >> (8 * (b + 1))) == pfx);
            if (ok) atomicAdd(&hist[(u >> (8 * b)) & 255], 1u);
        }
        __syncthreads();
        if (tid == 0) {
            unsigned cum = 0, k = sh_k;
            for (unsigned d = 255;; --d) {
                unsigned c2 = cum + hist[d];
                if (c2 >= k || d == 0) { sh_k = k - cum; sh_prefix = (pfx << 8) | d; break; }
                cum = c2;
            }
        }
        __syncthreads();
    }
    const unsigned v512 = sh_prefix;

    // ---- compact all entries >= v512 into keys (score_bits<<32 | 8191-r) ----
    if (tid == 0) sh_cnt = 0;
    __syncthreads();
    for (int i = 0; i < 32; ++i) {
        int r = tid + 256 * i;
        unsigned u = __float_as_uint(pc[r]);
        if (u >= v512) {
            unsigned pos = atomicAdd(&sh_cnt, 1u);
            if (pos < 1024) skeys[pos] = ((unsigned long long)u << 32) | (unsigned)(8191 - r);
        }
    }
    __syncthreads();
    unsigned M = min(sh_cnt, 1024u);
    for (int i = tid; i < 1024; i += 256)
        if ((unsigned)i >= M) skeys[i] = 0ull;
    __syncthreads();

    // ---- bitonic sort 1024 keys descending ----
    for (int size = 2; size <= 1024; size <<= 1) {
        for (int stride = size >> 1; stride > 0; stride >>= 1) {
            __syncthreads();
            for (int t = tid; t < 512; t += 256) {
                int i = 2 * t - (t & (stride - 1));
                int j = i + stride;
                unsigned long long a = skeys[i], bb = skeys[j];
                bool desc = ((i & size) == 0);
                bool sw = desc ? (a < bb) : (a > bb);
                if (sw) { skeys[i] = bb; skeys[j] = a; }
            }
        }
    }
    __syncthreads();

    // ---- extract top-512, clip boxes, areas ----
    for (int i = tid; i < KPRE; i += 256) {
        unsigned long long key = skeys[i];
        unsigned u = (unsigned)(key >> 32);
        float val = __uint_as_float(u);
        int r = 8191 - (int)(key & 0xFFFFFFFFull);
        svals[i] = val; sridx[i] = r;
        svalid[i] = (val > 1e-5f) ? 1 : 0;
        float b0 = boxes[r * 4 + 0], b1 = boxes[r * 4 + 1];
        float b2 = boxes[r * 4 + 2], b3 = boxes[r * 4 + 3];
        float x1 = fminf(fmaxf(b0, 0.0f), 1000.0f);
        float y1 = fminf(fmaxf(b1, 0.0f), 800.0f);
        float x2 = fminf(fmaxf(b2, 0.0f), 1000.0f);
        float y2 = fminf(fmaxf(b3, 0.0f), 800.0f);
        bx1[i] = x1; by1[i] = y1; bx2[i] = x2; by2[i] = y2;
        barea[i] = (x2 - x1) * (y2 - y1);
    }
    __syncthreads();

    // ---- suppression bitmask (lower triangle of words only) ----
    for (int task = tid; task < KPRE * 8; task += 256) {
        int i = task >> 3, w = task & 7;
        unsigned long long bits = 0ull;
        if (w <= (i >> 6)) {
            float xi1 = bx1[i], yi1 = by1[i], xi2 = bx2[i], yi2 = by2[i], ai = barea[i];
            for (int j2 = 0; j2 < 64; ++j2) {
                int j = (w << 6) + j2;
                float xx1 = fmaxf(xi1, bx1[j]);
                float yy1 = fmaxf(yi1, by1[j]);
                float xx2 = fminf(xi2, bx2[j]);
                float yy2 = fminf(yi2, by2[j]);
                float ww = fmaxf(xx2 - xx1, 0.0f);
                float hh = fmaxf(yy2 - yy1, 0.0f);
                float inter = ww * hh;
                float iou = inter / (ai + barea[j] - inter + 1e-9f);
                if (iou > 0.5f) bits |= (1ull << j2);
            }
        }
        msk[i][w] = bits;
    }
    __syncthreads();

    // ---- greedy scan (wave 0): lane w holds kept-word w ----
    if (tid < 64) {
        unsigned long long keptw = 0ull;
        for (int i = 0; i < KPRE; ++i) {
            unsigned long long mm = (tid < 8) ? msk[i][tid] : 0ull;
            int sup = __any((keptw & mm) != 0ull);
            int keep = (svalid[i] != 0) && !sup;
            if (keep && tid == (i >> 6)) keptw |= (1ull << (i & 63));
            if (tid == 0) skeep[i] = keep;
        }
    }
    __syncthreads();

    // ---- append kept detections to global list ----
    for (int i = tid; i < KPRE; i += 256) {
        if (skeep[i]) {
            unsigned pos = atomicAdd(g_cnt, 1u);
            g_ls[pos] = svals[i];
            g_lp[pos] = (unsigned)(sridx[i] * C_N + c);
        }
    }
}

// ---------------------------------------------------------------------------
// kth = 100th largest among kept scores (0 if fewer than 100 kept)
// ---------------------------------------------------------------------------
__global__ __launch_bounds__(256) void kth_kernel(const float* __restrict__ g_ls,
                                                  const unsigned* __restrict__ g_cnt,
                                                  float* __restrict__ g_kth) {
    __shared__ unsigned hist[256];
    __shared__ unsigned sh_prefix, sh_k;
    int tid = threadIdx.x;
    unsigned n = *g_cnt;
    if (n < (unsigned)TOPK) { if (tid == 0) *g_kth = 0.0f; return; }
    if (tid == 0) { sh_prefix = 0u; sh_k = TOPK; }
    __syncthreads();
    for (int b = 3; b >= 0; --b) {
        hist[tid] = 0;
        __syncthreads();
        unsigned pfx = sh_prefix;
        for (unsigned i = tid; i < n; i += 256) {
            unsigned u = __float_as_uint(g_ls[i]);
            bool ok = (b == 3) || ((u >> (8 * (b + 1))) == pfx);
            if (ok) atomicAdd(&hist[(u >> (8 * b)) & 255], 1u);
        }
        __syncthreads();
        if (tid == 0) {
            unsigned cum = 0, k = sh_k;
            for (unsigned d = 255;; --d) {
                unsigned c2 = cum + hist[d];
                if (c2 >= k || d == 0) { sh_k = k - cum; sh_prefix = (pfx << 8) | d; break; }
                cum = c2;
            }
        }
        __syncthreads();
    }
    if (tid == 0) *g_kth = __uint_as_float(sh_prefix);
}

// ---------------------------------------------------------------------------
// scatter kept scores >= kth into zeroed output [R, C]
// ---------------------------------------------------------------------------
__global__ __launch_bounds__(256) void scatter_kernel(const float* __restrict__ g_ls,
                                                      const unsigned* __restrict__ g_lp,
                                                      const unsigned* __restrict__ g_cnt,
                                                      const float* __restrict__ g_kth,
                                                      float* __restrict__ out) {
    unsigned idx = blockIdx.x * 256 + threadIdx.x;
    unsigned n = *g_cnt;
    float kth = *g_kth;
    if (idx < n) {
        float s = g_ls[idx];
        if (s >= kth) out[g_lp[idx]] = s;
    }
}

// ---------------------------------------------------------------------------
extern "C" void kernel_launch(void* const* d_in, const int* in_sizes, int n_in,
                              void* d_out, int out_size, void* d_ws, size_t ws_size,
                              hipStream_t stream) {
    const float* x     = (const float*)d_in[0];
    const float* Wc    = (const float*)d_in[1];
    const float* bc    = (const float*)d_in[2];
    const float* Wd    = (const float*)d_in[3];
    const float* bd    = (const float*)d_in[4];
    const float* boxes = (const float*)d_in[5];
    float* out = (float*)d_out;

    char* w = (char*)d_ws;
    float* part = (float*)w;  w += (size_t)KSPLIT * R_N * NC2 * sizeof(float);   // 41.9 MB
    float* cls  = (float*)w;  w += (size_t)R_N * C_N * sizeof(float);            // 2.6 MB
    float* detT = (float*)w;  w += (size_t)C_N * R_N * sizeof(float);            // 2.6 MB
    float* P    = (float*)w;  w += (size_t)C_N * R_N * sizeof(float);            // 2.6 MB
    float* g_ls = (float*)w;  w += (size_t)LIST_CAP * sizeof(float);
    unsigned* g_lp = (unsigned*)w; w += (size_t)LIST_CAP * sizeof(unsigned);
    unsigned* g_cnt = (unsigned*)w; w += 256;
    float* g_kth = (float*)w;

    zero_kernel<<<(R_N * C_N) / 256, 256, 0, stream>>>(out, g_cnt);
    gemm_part<<<64 * KSPLIT, 256, 0, stream>>>(x, Wc, Wd, part);
    reduce_bias<<<(R_N * NC2) / 256, 256, 0, stream>>>(part, bc, bd, cls, detT);
    row_softmax<<<R_N / 4, 256, 0, stream>>>(cls, P);
    col_softmax_mul<<<C_N, 256, 0, stream>>>(detT, P);
    nms_kernel<<<C_N, 256, 0, stream>>>(P, boxes, g_ls, g_lp, g_cnt);
    kth_kernel<<<1, 256, 0, stream>>>(g_ls, g_cnt, g_kth);
    scatter_kernel<<<(LIST_CAP + 255) / 256, 256, 0, stream>>>(g_ls, g_lp, g_cnt, g_kth, out);
}

// Round 2
// 557.030 us; speedup vs baseline: 1.2271x; 1.2271x over previous
//
#include <hip/hip_runtime.h>
#include <hip/hip_bf16.h>
#include <math.h>

#define R_N 8192
#define D_K 4096
#define C_N 80
#define NC2 160          // both heads concatenated
#define KSPLIT 8
#define KSLICE (D_K / KSPLIT)   // 512
#define BK 32
#define BM 128
#define KPRE 512
#define TOPK 100
#define LIST_CAP (80 * 512)

// ---------------------------------------------------------------------------
// zero d_out + counter
// ---------------------------------------------------------------------------
__global__ __launch_bounds__(256) void zero_kernel(float* __restrict__ out, unsigned* __restrict__ cnt) {
    int idx = blockIdx.x * 256 + threadIdx.x;
    if (idx < R_N * C_N) out[idx] = 0.0f;
    if (blockIdx.x == 0 && threadIdx.x == 0) *cnt = 0u;
}

// ---------------------------------------------------------------------------
// fused dual GEMM (fp32), K-split into partials  (UNCHANGED — bit-exact path)
// ---------------------------------------------------------------------------
__global__ __launch_bounds__(256) void gemm_part(const float* __restrict__ x,
                                                 const float* __restrict__ Wc,
                                                 const float* __restrict__ Wd,
                                                 float* __restrict__ part) {
    __shared__ float xs[BK][BM + 4];
    __shared__ float ws[BK][NC2 + 4];

    const int b   = blockIdx.x;
    const int rb  = b & 63;
    const int ks  = b >> 6;
    const int row0 = rb * BM;
    const int kbase = ks * KSLICE;
    const int tid = threadIdx.x;
    const int rg = tid >> 4, cg = tid & 15;
    const int r0 = rg * 8, c0 = cg * 10;

    float acc[8][10];
#pragma unroll
    for (int i = 0; i < 8; ++i)
#pragma unroll
        for (int j = 0; j < 10; ++j) acc[i][j] = 0.0f;

    for (int ch = 0; ch < KSLICE / BK; ++ch) {
        const int k0 = kbase + ch * BK;
#pragma unroll
        for (int i = 0; i < 4; ++i) {
            int li = tid + 256 * i;
            int r = li >> 3, v = li & 7;
            float4 t4 = *(const float4*)(x + (size_t)(row0 + r) * D_K + k0 + v * 4);
            int kk = v * 4;
            xs[kk + 0][r] = t4.x; xs[kk + 1][r] = t4.y;
            xs[kk + 2][r] = t4.z; xs[kk + 3][r] = t4.w;
        }
#pragma unroll
        for (int i = 0; i < 5; ++i) {
            int li = tid + 256 * i;
            int kk = li / 40, q = li % 40;
            const float* src = (q < 20) ? (Wc + (size_t)(k0 + kk) * C_N + q * 4)
                                        : (Wd + (size_t)(k0 + kk) * C_N + (q - 20) * 4);
            float4 t4 = *(const float4*)src;
            int cc = (q < 20) ? q * 4 : C_N + (q - 20) * 4;
            *(float4*)&ws[kk][cc] = t4;
        }
        __syncthreads();
#pragma unroll 4
        for (int kk = 0; kk < BK; ++kk) {
            float4 xa = *(const float4*)&xs[kk][r0];
            float4 xb = *(const float4*)&xs[kk][r0 + 4];
            float a[8] = {xa.x, xa.y, xa.z, xa.w, xb.x, xb.y, xb.z, xb.w};
            float w[10];
#pragma unroll
            for (int j = 0; j < 5; ++j) {
                float2 w2 = *(const float2*)&ws[kk][c0 + 2 * j];
                w[2 * j] = w2.x; w[2 * j + 1] = w2.y;
            }
#pragma unroll
            for (int rr = 0; rr < 8; ++rr)
#pragma unroll
                for (int j = 0; j < 10; ++j)
                    acc[rr][j] = fmaf(a[rr], w[j], acc[rr][j]);
        }
        __syncthreads();
    }
#pragma unroll
    for (int rr = 0; rr < 8; ++rr) {
        size_t base = ((size_t)ks * R_N + row0 + r0 + rr) * NC2 + c0;
#pragma unroll
        for (int j = 0; j < 5; ++j)
            *(float2*)(part + base + 2 * j) = make_float2(acc[rr][2 * j], acc[rr][2 * j + 1]);
    }
}

// ---------------------------------------------------------------------------
// reduce K-split partials (pairwise tree, deterministic), add bias, route
// ---------------------------------------------------------------------------
__global__ __launch_bounds__(256) void reduce_bias(const float* __restrict__ part,
                                                   const float* __restrict__ bc,
                                                   const float* __restrict__ bd,
                                                   float* __restrict__ cls,
                                                   float* __restrict__ detT) {
    const size_t STRIDE = (size_t)R_N * NC2;
    size_t idx = (size_t)blockIdx.x * 256 + threadIdx.x;
    int row = (int)(idx / NC2), col = (int)(idx % NC2);
    float p0 = part[idx + 0 * STRIDE], p1 = part[idx + 1 * STRIDE];
    float p2 = part[idx + 2 * STRIDE], p3 = part[idx + 3 * STRIDE];
    float p4 = part[idx + 4 * STRIDE], p5 = part[idx + 5 * STRIDE];
    float p6 = part[idx + 6 * STRIDE], p7 = part[idx + 7 * STRIDE];
    float s = ((p0 + p1) + (p2 + p3)) + ((p4 + p5) + (p6 + p7));
    if (col < C_N) {
        cls[(size_t)row * C_N + col] = s + bc[col];
    } else {
        detT[(size_t)(col - C_N) * R_N + row] = s + bd[col - C_N];
    }
}

// ---------------------------------------------------------------------------
// softmax over classes (axis=1); writes result transposed into P [C][R]
// ---------------------------------------------------------------------------
__global__ __launch_bounds__(256) void row_softmax(const float* __restrict__ cls,
                                                   float* __restrict__ P) {
    int tid = threadIdx.x;
    int wave = tid >> 6, lane = tid & 63;
    int row = blockIdx.x * 4 + wave;
    float v0 = cls[(size_t)row * C_N + lane];
    float v1 = (lane < 16) ? cls[(size_t)row * C_N + 64 + lane] : -INFINITY;
    float m = fmaxf(v0, v1);
#pragma unroll
    for (int off = 32; off > 0; off >>= 1) m = fmaxf(m, __shfl_xor(m, off, 64));
    float e0 = expf(v0 - m);
    float e1 = (lane < 16) ? expf(v1 - m) : 0.0f;
    float s = e0 + e1;
#pragma unroll
    for (int off = 32; off > 0; off >>= 1) s += __shfl_xor(s, off, 64);
    P[(size_t)lane * R_N + row] = e0 / s;
    if (lane < 16) P[(size_t)(64 + lane) * R_N + row] = e1 / s;
}

// ---------------------------------------------------------------------------
// softmax over proposals (axis=0) per class, multiplied into P
// ---------------------------------------------------------------------------
__global__ __launch_bounds__(256) void col_softmax_mul(const float* __restrict__ detT,
                                                       float* __restrict__ P) {
    __shared__ float red[256];
    int c = blockIdx.x, tid = threadIdx.x;
    const float* dc = detT + (size_t)c * R_N;
    float m = -INFINITY;
    for (int r = tid; r < R_N; r += 256) m = fmaxf(m, dc[r]);
    red[tid] = m; __syncthreads();
    for (int s2 = 128; s2 > 0; s2 >>= 1) {
        if (tid < s2) red[tid] = fmaxf(red[tid], red[tid + s2]);
        __syncthreads();
    }
    m = red[0]; __syncthreads();
    float sum = 0.0f;
    for (int r = tid; r < R_N; r += 256) sum += expf(dc[r] - m);
    red[tid] = sum; __syncthreads();
    for (int s2 = 128; s2 > 0; s2 >>= 1) {
        if (tid < s2) red[tid] += red[tid + s2];
        __syncthreads();
    }
    float s = red[0];
    float* pc = P + (size_t)c * R_N;
    for (int r = tid; r < R_N; r += 256) pc[r] = pc[r] * (expf(dc[r] - m) / s);
}

// ---------------------------------------------------------------------------
// Stage A: per (class, chunk of 1024) bitonic sort of composite keys,
// emit sorted top-512. key = (score_bits << 32) | (8191 - r)  -> sorting
// descending reproduces jax.lax.top_k order incl. lower-index-first ties.
// grid = 80*8 blocks
// ---------------------------------------------------------------------------
__global__ __launch_bounds__(256) void chunk_sort(const float* __restrict__ P,
                                                  unsigned long long* __restrict__ cand) {
    __shared__ unsigned long long sk[1024];
    const int c = blockIdx.x >> 3, ch = blockIdx.x & 7;
    const int tid = threadIdx.x;
    const float* pc = P + (size_t)c * R_N + ch * 1024;

    for (int i = tid; i < 1024; i += 256) {
        unsigned u = __float_as_uint(pc[i]);
        int r = ch * 1024 + i;
        sk[i] = ((unsigned long long)u << 32) | (unsigned)(8191 - r);
    }
    __syncthreads();
    for (int size = 2; size <= 1024; size <<= 1) {
        for (int stride = size >> 1; stride > 0; stride >>= 1) {
            for (int t = tid; t < 512; t += 256) {
                int i = 2 * t - (t & (stride - 1));
                int j = i + stride;
                unsigned long long a = sk[i], b = sk[j];
                bool desc = ((i & size) == 0);
                if ((a < b) == desc) { sk[i] = b; sk[j] = a; }
            }
            __syncthreads();
        }
    }
    unsigned long long* dst = cand + (size_t)blockIdx.x * 512;
    for (int i = tid; i < 512; i += 256) dst[i] = sk[i];
}

// ---------------------------------------------------------------------------
// Stage B: fold 8 sorted 512-lists into the exact class top-512 (7 bitonic
// merges), then extract vals/ridx/clipped boxes and the valid-prefix length.
// grid = 80 blocks
// ---------------------------------------------------------------------------
__global__ __launch_bounds__(256) void merge_extract(const unsigned long long* __restrict__ cand,
                                                     const float* __restrict__ boxes,
                                                     float* __restrict__ svals,
                                                     int* __restrict__ sridx,
                                                     float* __restrict__ cbox,
                                                     int* __restrict__ nvalid) {
    __shared__ unsigned long long A[1024];
    const int c = blockIdx.x, tid = threadIdx.x;
    const unsigned long long* base = cand + (size_t)c * 8 * 512;

    for (int i = tid; i < 512; i += 256) A[i] = base[i];
    for (int l = 1; l < 8; ++l) {
        __syncthreads();
        // append next list reversed (ascending) -> bitonic sequence of 1024
        for (int i = tid; i < 512; i += 256) A[512 + i] = base[l * 512 + (511 - i)];
        __syncthreads();
        for (int stride = 512; stride > 0; stride >>= 1) {
            for (int t = tid; t < 512; t += 256) {
                int i = 2 * t - (t & (stride - 1));
                int j = i + stride;
                unsigned long long a = A[i], b = A[j];
                if (a < b) { A[i] = b; A[j] = a; }   // keep max at low index (desc)
            }
            __syncthreads();
        }
        // A[0:512] now = top-512 of prefix, sorted desc
    }
    __syncthreads();
    for (int i = tid; i < 512; i += 256) {
        unsigned long long k = A[i];
        float v = __uint_as_float((unsigned)(k >> 32));
        int r = 8191 - (int)(k & 0xFFFFFFFFull);
        svals[c * 512 + i] = v;
        sridx[c * 512 + i] = r;
        float b0 = boxes[r * 4 + 0], b1 = boxes[r * 4 + 1];
        float b2 = boxes[r * 4 + 2], b3 = boxes[r * 4 + 3];
        float4 cb;
        cb.x = fminf(fmaxf(b0, 0.0f), 1000.0f);
        cb.y = fminf(fmaxf(b1, 0.0f), 800.0f);
        cb.z = fminf(fmaxf(b2, 0.0f), 1000.0f);
        cb.w = fminf(fmaxf(b3, 0.0f), 800.0f);
        *(float4*)&cbox[((size_t)c * 512 + i) * 4] = cb;
        // valid prefix boundary (values sorted desc -> predicate is a prefix)
        float vn = (i < 511) ? __uint_as_float((unsigned)(A[i + 1] >> 32)) : -1.0f;
        if (v > 1e-5f && !(vn > 1e-5f)) nvalid[c] = i + 1;
        if (i == 0 && !(v > 1e-5f)) nvalid[c] = 0;
    }
}

// ---------------------------------------------------------------------------
// Stage C: suppression bitmask to global. grid = 80*8 blocks: (class, word w).
// Row i only needs words w <= i>>6 and only rows i < nvalid; rest written 0.
// ---------------------------------------------------------------------------
__global__ __launch_bounds__(256) void iou_mask(const float* __restrict__ cbox,
                                                const int* __restrict__ nvalid,
                                                unsigned long long* __restrict__ gmask) {
    __shared__ float sx1[512], sy1[512], sx2[512], sy2[512], sar[512];
    const int c = blockIdx.x >> 3, w = blockIdx.x & 7;
    const int tid = threadIdx.x;
    const int nv = nvalid[c];

    for (int i = tid; i < 512; i += 256) {
        float4 b = *(const float4*)&cbox[((size_t)c * 512 + i) * 4];
        sx1[i] = b.x; sy1[i] = b.y; sx2[i] = b.z; sy2[i] = b.w;
        sar[i] = (b.z - b.x) * (b.w - b.y);
    }
    __syncthreads();
    for (int i = tid; i < 512; i += 256) {
        unsigned long long bits = 0ull;
        if (i < nv && w <= (i >> 6)) {
            float xi1 = sx1[i], yi1 = sy1[i], xi2 = sx2[i], yi2 = sy2[i], ai = sar[i];
#pragma unroll 8
            for (int j2 = 0; j2 < 64; ++j2) {
                int j = (w << 6) + j2;
                float xx1 = fmaxf(xi1, sx1[j]);
                float yy1 = fmaxf(yi1, sy1[j]);
                float xx2 = fminf(xi2, sx2[j]);
                float yy2 = fminf(yi2, sy2[j]);
                float ww = fmaxf(xx2 - xx1, 0.0f);
                float hh = fmaxf(yy2 - yy1, 0.0f);
                float inter = ww * hh;
                float iou = inter / (ai + sar[j] - inter + 1e-9f);
                if (iou > 0.5f) bits |= (1ull << j2);
            }
        }
        gmask[((size_t)c * 512 + i) * 8 + w] = bits;
    }
}

// ---------------------------------------------------------------------------
// Stage D: greedy scan. One wave per class; mask in LDS; 8-deep prefetch
// keeps ds_read latency off the dependent chain. Append kept to global list.
// ---------------------------------------------------------------------------
__global__ __launch_bounds__(64) void nms_scan(const unsigned long long* __restrict__ gmask,
                                               const float* __restrict__ svals,
                                               const int* __restrict__ sridx,
                                               const int* __restrict__ nvalid,
                                               float* __restrict__ g_ls,
                                               unsigned* __restrict__ g_lp,
                                               unsigned* __restrict__ g_cnt) {
    __shared__ unsigned long long sm[512 * 8];   // 32 KB
    __shared__ unsigned char keepf[512];
    const int c = blockIdx.x, lane = threadIdx.x;
    const int nv = nvalid[c];
    const unsigned long long* gm = gmask + (size_t)c * 512 * 8;

    for (int t = lane; t < 4096; t += 64) sm[t] = gm[t];
    __syncthreads();

    const bool rd = (lane < 8);
    unsigned long long keptw = 0ull;
    unsigned long long pf[8];
#pragma unroll
    for (int d = 0; d < 8; ++d) pf[d] = rd ? sm[(d & 511) * 8 + lane] : 0ull;
    for (int i = 0; i < nv; ++i) {
        unsigned long long mm = pf[i & 7];
        int ip = (i + 8) & 511;
        pf[i & 7] = rd ? sm[ip * 8 + lane] : 0ull;
        int sup = __any((keptw & mm) != 0ull);
        int keep = !sup;
        if (keep && lane == (i >> 6)) keptw |= (1ull << (i & 63));
        if (lane == 0) keepf[i] = (unsigned char)keep;
    }
    __syncthreads();
    for (int i = lane; i < nv; i += 64) {
        if (keepf[i]) {
            unsigned pos = atomicAdd(g_cnt, 1u);
            g_ls[pos] = svals[c * 512 + i];
            g_lp[pos] = (unsigned)(sridx[c * 512 + i] * C_N + c);
        }
    }
}

// ---------------------------------------------------------------------------
// kth = 100th largest among kept scores (0 if fewer than 100 kept)
// ---------------------------------------------------------------------------
__global__ __launch_bounds__(256) void kth_kernel(const float* __restrict__ g_ls,
                                                  const unsigned* __restrict__ g_cnt,
                                                  float* __restrict__ g_kth) {
    __shared__ unsigned hist[256];
    __shared__ unsigned sh_prefix, sh_k;
    int tid = threadIdx.x;
    unsigned n = *g_cnt;
    if (n < (unsigned)TOPK) { if (tid == 0) *g_kth = 0.0f; return; }
    if (tid == 0) { sh_prefix = 0u; sh_k = TOPK; }
    __syncthreads();
    for (int b = 3; b >= 0; --b) {
        hist[tid] = 0;
        __syncthreads();
        unsigned pfx = sh_prefix;
        for (unsigned i = tid; i < n; i += 256) {
            unsigned u = __float_as_uint(g_ls[i]);
            bool ok = (b == 3) || ((u >> (8 * (b + 1))) == pfx);
            if (ok) atomicAdd(&hist[(u >> (8 * b)) & 255], 1u);
        }
        __syncthreads();
        if (tid == 0) {
            unsigned cum = 0, k = sh_k;
            for (unsigned d = 255;; --d) {
                unsigned c2 = cum + hist[d];
                if (c2 >= k || d == 0) { sh_k = k - cum; sh_prefix = (pfx << 8) | d; break; }
                cum = c2;
            }
        }
        __syncthreads();
    }
    if (tid == 0) *g_kth = __uint_as_float(sh_prefix);
}

// ---------------------------------------------------------------------------
// scatter kept scores >= kth into zeroed output [R, C]
// ---------------------------------------------------------------------------
__global__ __launch_bounds__(256) void scatter_kernel(const float* __restrict__ g_ls,
                                                      const unsigned* __restrict__ g_lp,
                                                      const unsigned* __restrict__ g_cnt,
                                                      const float* __restrict__ g_kth,
                                                      float* __restrict__ out) {
    unsigned idx = blockIdx.x * 256 + threadIdx.x;
    unsigned n = *g_cnt;
    float kth = *g_kth;
    if (idx < n) {
        float s = g_ls[idx];
        if (s >= kth) out[g_lp[idx]] = s;
    }
}

// ---------------------------------------------------------------------------
extern "C" void kernel_launch(void* const* d_in, const int* in_sizes, int n_in,
                              void* d_out, int out_size, void* d_ws, size_t ws_size,
                              hipStream_t stream) {
    const float* x     = (const float*)d_in[0];
    const float* Wc    = (const float*)d_in[1];
    const float* bc    = (const float*)d_in[2];
    const float* Wd    = (const float*)d_in[3];
    const float* bd    = (const float*)d_in[4];
    const float* boxes = (const float*)d_in[5];
    float* out = (float*)d_out;

    char* w = (char*)d_ws;
    float* part = (float*)w;  w += (size_t)KSPLIT * R_N * NC2 * sizeof(float);   // 41.9 MB (dead after reduce_bias)
    float* cls  = (float*)w;  w += (size_t)R_N * C_N * sizeof(float);
    float* detT = (float*)w;  w += (size_t)C_N * R_N * sizeof(float);
    float* P    = (float*)w;  w += (size_t)C_N * R_N * sizeof(float);
    float* g_ls = (float*)w;  w += (size_t)LIST_CAP * sizeof(float);
    unsigned* g_lp = (unsigned*)w; w += (size_t)LIST_CAP * sizeof(unsigned);
    unsigned* g_cnt = (unsigned*)w; w += 256;
    float* g_kth = (float*)w; w += 256;

    // NMS scratch aliases the dead `part` region (first use is after reduce_bias)
    char* a = (char*)part;
    unsigned long long* cand = (unsigned long long*)a; a += (size_t)C_N * 8 * 512 * sizeof(unsigned long long); // 2.62 MB
    float* svals = (float*)a;  a += (size_t)C_N * KPRE * sizeof(float);
    int*   sridx = (int*)a;    a += (size_t)C_N * KPRE * sizeof(int);
    float* cbox  = (float*)a;  a += (size_t)C_N * KPRE * 4 * sizeof(float);
    int*   nvalid = (int*)a;   a += 4096;
    unsigned long long* gmask = (unsigned long long*)a; a += (size_t)C_N * KPRE * 8 * sizeof(unsigned long long); // 2.62 MB

    zero_kernel<<<(R_N * C_N) / 256, 256, 0, stream>>>(out, g_cnt);
    gemm_part<<<64 * KSPLIT, 256, 0, stream>>>(x, Wc, Wd, part);
    reduce_bias<<<(R_N * NC2) / 256, 256, 0, stream>>>(part, bc, bd, cls, detT);
    row_softmax<<<R_N / 4, 256, 0, stream>>>(cls, P);
    col_softmax_mul<<<C_N, 256, 0, stream>>>(detT, P);
    chunk_sort<<<C_N * 8, 256, 0, stream>>>(P, cand);
    merge_extract<<<C_N, 256, 0, stream>>>(cand, boxes, svals, sridx, cbox, nvalid);
    iou_mask<<<C_N * 8, 256, 0, stream>>>(cbox, nvalid, gmask);
    nms_scan<<<C_N, 64, 0, stream>>>(gmask, svals, sridx, nvalid, g_ls, g_lp, g_cnt);
    kth_kernel<<<1, 256, 0, stream>>>(g_ls, g_cnt, g_kth);
    scatter_kernel<<<(LIST_CAP + 255) / 256, 256, 0, stream>>>(g_ls, g_lp, g_cnt, g_kth, out);
}

// Round 3
// 511.461 us; speedup vs baseline: 1.3364x; 1.0891x over previous
//
#include <hip/hip_runtime.h>
#include <hip/hip_bf16.h>
#include <math.h>

#define R_N 8192
#define D_K 4096
#define C_N 80
#define NC2 160          // both heads concatenated
#define KSPLIT 8
#define KSLICE (D_K / KSPLIT)   // 512
#define KPRE 512
#define TOPK 100
#define LIST_CAP (80 * 512)

typedef _Float16 f16;
typedef f16 f16x8 __attribute__((ext_vector_type(8)));
typedef f16 f16x4 __attribute__((ext_vector_type(4)));
typedef float f32x4 __attribute__((ext_vector_type(4)));

#define LDA 40   // padded k-stride (f16 elems): 32 + 8 -> rows 80B apart, 2-way banks (free)

// ---------------------------------------------------------------------------
// zero d_out + counter
// ---------------------------------------------------------------------------
__global__ __launch_bounds__(256) void zero_kernel(float* __restrict__ out, unsigned* __restrict__ cnt) {
    int idx = blockIdx.x * 256 + threadIdx.x;
    if (idx < R_N * C_N) out[idx] = 0.0f;
    if (blockIdx.x == 0 && threadIdx.x == 0) *cnt = 0u;
}

// ---------------------------------------------------------------------------
// fused dual GEMM via f16 split-2 MFMA (3 passes: lo*hi + hi*lo + hi*hi),
// K-split into fp32 partials [KSPLIT][R][160].
// grid: 64 row-blocks x 8 K-slices; 256 threads (4 waves).
// wave w: rows [32w,32w+32) (2 row-tiles of 16), all 160 cols (10 col-tiles).
// mfma_f32_16x16x32_f16: A[m=lane&15][k=quad*8+j], B[k=quad*8+j][n=lane&15],
// C/D: col=lane&15, row=quad*4+reg.
// ---------------------------------------------------------------------------
__global__ __launch_bounds__(256) void gemm_part(const float* __restrict__ x,
                                                 const float* __restrict__ Wc,
                                                 const float* __restrict__ Wd,
                                                 float* __restrict__ part) {
    __shared__ __align__(16) f16 Ah[128 * LDA];
    __shared__ __align__(16) f16 Al[128 * LDA];
    __shared__ __align__(16) f16 Bh[160 * LDA];
    __shared__ __align__(16) f16 Bl[160 * LDA];

    const int b    = blockIdx.x;
    const int rb   = b & 63;
    const int ks   = b >> 6;
    const int row0 = rb * 128;
    const int kbase = ks * KSLICE;
    const int tid  = threadIdx.x;
    const int wv   = tid >> 6, lane = tid & 63;
    const int m    = lane & 15, quad = lane >> 4;

    f32x4 acc[2][10];
#pragma unroll
    for (int t = 0; t < 2; ++t)
#pragma unroll
        for (int n = 0; n < 10; ++n) acc[t][n] = (f32x4)(0.0f);

    for (int ch = 0; ch < KSLICE / 32; ++ch) {
        const int k0 = kbase + ch * 32;
        // ---- stage A: 128 rows x 32 k fp32 -> hi/lo f16 ----
#pragma unroll
        for (int i = 0; i < 4; ++i) {
            int li = tid + 256 * i;
            int r = li >> 3, v = li & 7;
            float4 t4 = *(const float4*)(x + (size_t)(row0 + r) * D_K + k0 + v * 4);
            float tv[4] = {t4.x, t4.y, t4.z, t4.w};
            f16x4 hv, lv;
#pragma unroll
            for (int j = 0; j < 4; ++j) {
                f16 h = (f16)tv[j];
                hv[j] = h;
                lv[j] = (f16)(tv[j] - (float)h);
            }
            *(f16x4*)&Ah[r * LDA + v * 4] = hv;
            *(f16x4*)&Al[r * LDA + v * 4] = lv;
        }
        // ---- stage B: 32 k x 160 cols (Wc|Wd) -> transposed hi/lo f16 ----
#pragma unroll
        for (int i = 0; i < 5; ++i) {
            int li = tid + 256 * i;           // 0..1279
            int hd = (li >= 640) ? 1 : 0;
            int l2 = li - hd * 640;
            int kk = l2 / 20, qn = l2 % 20;
            const float* src = hd ? Wd : Wc;
            float4 t4 = *(const float4*)(src + (size_t)(k0 + kk) * C_N + qn * 4);
            float tv[4] = {t4.x, t4.y, t4.z, t4.w};
            int nb = hd * 80 + qn * 4;
#pragma unroll
            for (int j = 0; j < 4; ++j) {
                f16 h = (f16)tv[j];
                Bh[(nb + j) * LDA + kk] = h;
                Bl[(nb + j) * LDA + kk] = (f16)(tv[j] - (float)h);
            }
        }
        __syncthreads();
        // ---- fragments + MFMA ----
        f16x8 ah[2], al[2];
#pragma unroll
        for (int t = 0; t < 2; ++t) {
            int r = wv * 32 + t * 16 + m;
            ah[t] = *(const f16x8*)&Ah[r * LDA + quad * 8];
            al[t] = *(const f16x8*)&Al[r * LDA + quad * 8];
        }
#pragma unroll
        for (int n = 0; n < 10; ++n) {
            int nn = n * 16 + m;
            f16x8 bh = *(const f16x8*)&Bh[nn * LDA + quad * 8];
            f16x8 bl = *(const f16x8*)&Bl[nn * LDA + quad * 8];
#pragma unroll
            for (int t = 0; t < 2; ++t) {
                acc[t][n] = __builtin_amdgcn_mfma_f32_16x16x32_f16(al[t], bh, acc[t][n], 0, 0, 0);
                acc[t][n] = __builtin_amdgcn_mfma_f32_16x16x32_f16(ah[t], bl, acc[t][n], 0, 0, 0);
                acc[t][n] = __builtin_amdgcn_mfma_f32_16x16x32_f16(ah[t], bh, acc[t][n], 0, 0, 0);
            }
        }
        __syncthreads();
    }
    // ---- epilogue: scatter C/D fragments to partials ----
#pragma unroll
    for (int t = 0; t < 2; ++t) {
        int grow0 = row0 + wv * 32 + t * 16 + quad * 4;
#pragma unroll
        for (int n = 0; n < 10; ++n) {
            int gcol = n * 16 + m;
#pragma unroll
            for (int r4 = 0; r4 < 4; ++r4)
                part[((size_t)ks * R_N + grow0 + r4) * NC2 + gcol] = acc[t][n][r4];
        }
    }
}

// ---------------------------------------------------------------------------
// reduce K-split partials (pairwise tree, deterministic), add bias, route
// ---------------------------------------------------------------------------
__global__ __launch_bounds__(256) void reduce_bias(const float* __restrict__ part,
                                                   const float* __restrict__ bc,
                                                   const float* __restrict__ bd,
                                                   float* __restrict__ cls,
                                                   float* __restrict__ detT) {
    const size_t STRIDE = (size_t)R_N * NC2;
    size_t idx = (size_t)blockIdx.x * 256 + threadIdx.x;
    int row = (int)(idx / NC2), col = (int)(idx % NC2);
    float p0 = part[idx + 0 * STRIDE], p1 = part[idx + 1 * STRIDE];
    float p2 = part[idx + 2 * STRIDE], p3 = part[idx + 3 * STRIDE];
    float p4 = part[idx + 4 * STRIDE], p5 = part[idx + 5 * STRIDE];
    float p6 = part[idx + 6 * STRIDE], p7 = part[idx + 7 * STRIDE];
    float s = ((p0 + p1) + (p2 + p3)) + ((p4 + p5) + (p6 + p7));
    if (col < C_N) {
        cls[(size_t)row * C_N + col] = s + bc[col];
    } else {
        detT[(size_t)(col - C_N) * R_N + row] = s + bd[col - C_N];
    }
}

// ---------------------------------------------------------------------------
// softmax over classes (axis=1); writes result transposed into P [C][R]
// ---------------------------------------------------------------------------
__global__ __launch_bounds__(256) void row_softmax(const float* __restrict__ cls,
                                                   float* __restrict__ P) {
    int tid = threadIdx.x;
    int wave = tid >> 6, lane = tid & 63;
    int row = blockIdx.x * 4 + wave;
    float v0 = cls[(size_t)row * C_N + lane];
    float v1 = (lane < 16) ? cls[(size_t)row * C_N + 64 + lane] : -INFINITY;
    float m = fmaxf(v0, v1);
#pragma unroll
    for (int off = 32; off > 0; off >>= 1) m = fmaxf(m, __shfl_xor(m, off, 64));
    float e0 = expf(v0 - m);
    float e1 = (lane < 16) ? expf(v1 - m) : 0.0f;
    float s = e0 + e1;
#pragma unroll
    for (int off = 32; off > 0; off >>= 1) s += __shfl_xor(s, off, 64);
    P[(size_t)lane * R_N + row] = e0 / s;
    if (lane < 16) P[(size_t)(64 + lane) * R_N + row] = e1 / s;
}

// ---------------------------------------------------------------------------
// softmax over proposals (axis=0) per class, multiplied into P
// ---------------------------------------------------------------------------
__global__ __launch_bounds__(256) void col_softmax_mul(const float* __restrict__ detT,
                                                       float* __restrict__ P) {
    __shared__ float red[256];
    int c = blockIdx.x, tid = threadIdx.x;
    const float* dc = detT + (size_t)c * R_N;
    float m = -INFINITY;
    for (int r = tid; r < R_N; r += 256) m = fmaxf(m, dc[r]);
    red[tid] = m; __syncthreads();
    for (int s2 = 128; s2 > 0; s2 >>= 1) {
        if (tid < s2) red[tid] = fmaxf(red[tid], red[tid + s2]);
        __syncthreads();
    }
    m = red[0]; __syncthreads();
    float sum = 0.0f;
    for (int r = tid; r < R_N; r += 256) sum += expf(dc[r] - m);
    red[tid] = sum; __syncthreads();
    for (int s2 = 128; s2 > 0; s2 >>= 1) {
        if (tid < s2) red[tid] += red[tid + s2];
        __syncthreads();
    }
    float s = red[0];
    float* pc = P + (size_t)c * R_N;
    for (int r = tid; r < R_N; r += 256) pc[r] = pc[r] * (expf(dc[r] - m) / s);
}

// ---------------------------------------------------------------------------
// Stage A: per (class, chunk of 1024) bitonic sort of composite keys,
// emit sorted top-512. key = (score_bits << 32) | (8191 - r).
// ---------------------------------------------------------------------------
__global__ __launch_bounds__(256) void chunk_sort(const float* __restrict__ P,
                                                  unsigned long long* __restrict__ cand) {
    __shared__ unsigned long long sk[1024];
    const int c = blockIdx.x >> 3, ch = blockIdx.x & 7;
    const int tid = threadIdx.x;
    const float* pc = P + (size_t)c * R_N + ch * 1024;

    for (int i = tid; i < 1024; i += 256) {
        unsigned u = __float_as_uint(pc[i]);
        int r = ch * 1024 + i;
        sk[i] = ((unsigned long long)u << 32) | (unsigned)(8191 - r);
    }
    __syncthreads();
    for (int size = 2; size <= 1024; size <<= 1) {
        for (int stride = size >> 1; stride > 0; stride >>= 1) {
            for (int t = tid; t < 512; t += 256) {
                int i = 2 * t - (t & (stride - 1));
                int j = i + stride;
                unsigned long long a = sk[i], b = sk[j];
                bool desc = ((i & size) == 0);
                if ((a < b) == desc) { sk[i] = b; sk[j] = a; }
            }
            __syncthreads();
        }
    }
    unsigned long long* dst = cand + (size_t)blockIdx.x * 512;
    for (int i = tid; i < 512; i += 256) dst[i] = sk[i];
}

// ---------------------------------------------------------------------------
// Stage B: fold 8 sorted 512-lists into the exact class top-512.
// ---------------------------------------------------------------------------
__global__ __launch_bounds__(256) void merge_extract(const unsigned long long* __restrict__ cand,
                                                     const float* __restrict__ boxes,
                                                     float* __restrict__ svals,
                                                     int* __restrict__ sridx,
                                                     float* __restrict__ cbox,
                                                     int* __restrict__ nvalid) {
    __shared__ unsigned long long A[1024];
    const int c = blockIdx.x, tid = threadIdx.x;
    const unsigned long long* base = cand + (size_t)c * 8 * 512;

    for (int i = tid; i < 512; i += 256) A[i] = base[i];
    for (int l = 1; l < 8; ++l) {
        __syncthreads();
        for (int i = tid; i < 512; i += 256) A[512 + i] = base[l * 512 + (511 - i)];
        __syncthreads();
        for (int stride = 512; stride > 0; stride >>= 1) {
            for (int t = tid; t < 512; t += 256) {
                int i = 2 * t - (t & (stride - 1));
                int j = i + stride;
                unsigned long long a = A[i], b = A[j];
                if (a < b) { A[i] = b; A[j] = a; }
            }
            __syncthreads();
        }
    }
    __syncthreads();
    for (int i = tid; i < 512; i += 256) {
        unsigned long long k = A[i];
        float v = __uint_as_float((unsigned)(k >> 32));
        int r = 8191 - (int)(k & 0xFFFFFFFFull);
        svals[c * 512 + i] = v;
        sridx[c * 512 + i] = r;
        float b0 = boxes[r * 4 + 0], b1 = boxes[r * 4 + 1];
        float b2 = boxes[r * 4 + 2], b3 = boxes[r * 4 + 3];
        float4 cb;
        cb.x = fminf(fmaxf(b0, 0.0f), 1000.0f);
        cb.y = fminf(fmaxf(b1, 0.0f), 800.0f);
        cb.z = fminf(fmaxf(b2, 0.0f), 1000.0f);
        cb.w = fminf(fmaxf(b3, 0.0f), 800.0f);
        *(float4*)&cbox[((size_t)c * 512 + i) * 4] = cb;
        float vn = (i < 511) ? __uint_as_float((unsigned)(A[i + 1] >> 32)) : -1.0f;
        if (v > 1e-5f && !(vn > 1e-5f)) nvalid[c] = i + 1;
        if (i == 0 && !(v > 1e-5f)) nvalid[c] = 0;
    }
}

// ---------------------------------------------------------------------------
// Stage C: suppression bitmask to global. grid = 80*8: (class, word w).
// ---------------------------------------------------------------------------
__global__ __launch_bounds__(256) void iou_mask(const float* __restrict__ cbox,
                                                const int* __restrict__ nvalid,
                                                unsigned long long* __restrict__ gmask) {
    __shared__ float sx1[512], sy1[512], sx2[512], sy2[512], sar[512];
    const int c = blockIdx.x >> 3, w = blockIdx.x & 7;
    const int tid = threadIdx.x;
    const int nv = nvalid[c];

    for (int i = tid; i < 512; i += 256) {
        float4 b = *(const float4*)&cbox[((size_t)c * 512 + i) * 4];
        sx1[i] = b.x; sy1[i] = b.y; sx2[i] = b.z; sy2[i] = b.w;
        sar[i] = (b.z - b.x) * (b.w - b.y);
    }
    __syncthreads();
    for (int i = tid; i < 512; i += 256) {
        unsigned long long bits = 0ull;
        if (i < nv && w <= (i >> 6)) {
            float xi1 = sx1[i], yi1 = sy1[i], xi2 = sx2[i], yi2 = sy2[i], ai = sar[i];
#pragma unroll 8
            for (int j2 = 0; j2 < 64; ++j2) {
                int j = (w << 6) + j2;
                float xx1 = fmaxf(xi1, sx1[j]);
                float yy1 = fmaxf(yi1, sy1[j]);
                float xx2 = fminf(xi2, sx2[j]);
                float yy2 = fminf(yi2, sy2[j]);
                float ww = fmaxf(xx2 - xx1, 0.0f);
                float hh = fmaxf(yy2 - yy1, 0.0f);
                float inter = ww * hh;
                float iou = inter / (ai + sar[j] - inter + 1e-9f);
                if (iou > 0.5f) bits |= (1ull << j2);
            }
        }
        gmask[((size_t)c * 512 + i) * 8 + w] = bits;
    }
}

// ---------------------------------------------------------------------------
// Stage D: greedy scan, one wave per class, prefetched LDS mask.
// ---------------------------------------------------------------------------
__global__ __launch_bounds__(64) void nms_scan(const unsigned long long* __restrict__ gmask,
                                               const float* __restrict__ svals,
                                               const int* __restrict__ sridx,
                                               const int* __restrict__ nvalid,
                                               float* __restrict__ g_ls,
                                               unsigned* __restrict__ g_lp,
                                               unsigned* __restrict__ g_cnt) {
    __shared__ unsigned long long sm[512 * 8];
    __shared__ unsigned char keepf[512];
    const int c = blockIdx.x, lane = threadIdx.x;
    const int nv = nvalid[c];
    const unsigned long long* gm = gmask + (size_t)c * 512 * 8;

    for (int t = lane; t < 4096; t += 64) sm[t] = gm[t];
    __syncthreads();

    const bool rd = (lane < 8);
    unsigned long long keptw = 0ull;
    unsigned long long pf[8];
#pragma unroll
    for (int d = 0; d < 8; ++d) pf[d] = rd ? sm[(d & 511) * 8 + lane] : 0ull;
    for (int i = 0; i < nv; ++i) {
        unsigned long long mm = pf[i & 7];
        int ip = (i + 8) & 511;
        pf[i & 7] = rd ? sm[ip * 8 + lane] : 0ull;
        int sup = __any((keptw & mm) != 0ull);
        int keep = !sup;
        if (keep && lane == (i >> 6)) keptw |= (1ull << (i & 63));
        if (lane == 0) keepf[i] = (unsigned char)keep;
    }
    __syncthreads();
    for (int i = lane; i < nv; i += 64) {
        if (keepf[i]) {
            unsigned pos = atomicAdd(g_cnt, 1u);
            g_ls[pos] = svals[c * 512 + i];
            g_lp[pos] = (unsigned)(sridx[c * 512 + i] * C_N + c);
        }
    }
}

// ---------------------------------------------------------------------------
// kth = 100th largest among kept scores (0 if fewer than 100 kept)
// ---------------------------------------------------------------------------
__global__ __launch_bounds__(256) void kth_kernel(const float* __restrict__ g_ls,
                                                  const unsigned* __restrict__ g_cnt,
                                                  float* __restrict__ g_kth) {
    __shared__ unsigned hist[256];
    __shared__ unsigned sh_prefix, sh_k;
    int tid = threadIdx.x;
    unsigned n = *g_cnt;
    if (n < (unsigned)TOPK) { if (tid == 0) *g_kth = 0.0f; return; }
    if (tid == 0) { sh_prefix = 0u; sh_k = TOPK; }
    __syncthreads();
    for (int b = 3; b >= 0; --b) {
        hist[tid] = 0;
        __syncthreads();
        unsigned pfx = sh_prefix;
        for (unsigned i = tid; i < n; i += 256) {
            unsigned u = __float_as_uint(g_ls[i]);
            bool ok = (b == 3) || ((u >> (8 * (b + 1))) == pfx);
            if (ok) atomicAdd(&hist[(u >> (8 * b)) & 255], 1u);
        }
        __syncthreads();
        if (tid == 0) {
            unsigned cum = 0, k = sh_k;
            for (unsigned d = 255;; --d) {
                unsigned c2 = cum + hist[d];
                if (c2 >= k || d == 0) { sh_k = k - cum; sh_prefix = (pfx << 8) | d; break; }
                cum = c2;
            }
        }
        __syncthreads();
    }
    if (tid == 0) *g_kth = __uint_as_float(sh_prefix);
}

// ---------------------------------------------------------------------------
// scatter kept scores >= kth into zeroed output [R, C]
// ---------------------------------------------------------------------------
__global__ __launch_bounds__(256) void scatter_kernel(const float* __restrict__ g_ls,
                                                      const unsigned* __restrict__ g_lp,
                                                      const unsigned* __restrict__ g_cnt,
                                                      const float* __restrict__ g_kth,
                                                      float* __restrict__ out) {
    unsigned idx = blockIdx.x * 256 + threadIdx.x;
    unsigned n = *g_cnt;
    float kth = *g_kth;
    if (idx < n) {
        float s = g_ls[idx];
        if (s >= kth) out[g_lp[idx]] = s;
    }
}

// ---------------------------------------------------------------------------
extern "C" void kernel_launch(void* const* d_in, const int* in_sizes, int n_in,
                              void* d_out, int out_size, void* d_ws, size_t ws_size,
                              hipStream_t stream) {
    const float* x     = (const float*)d_in[0];
    const float* Wc    = (const float*)d_in[1];
    const float* bc    = (const float*)d_in[2];
    const float* Wd    = (const float*)d_in[3];
    const float* bd    = (const float*)d_in[4];
    const float* boxes = (const float*)d_in[5];
    float* out = (float*)d_out;

    char* w = (char*)d_ws;
    float* part = (float*)w;  w += (size_t)KSPLIT * R_N * NC2 * sizeof(float);   // 41.9 MB (dead after reduce_bias)
    float* cls  = (float*)w;  w += (size_t)R_N * C_N * sizeof(float);
    float* detT = (float*)w;  w += (size_t)C_N * R_N * sizeof(float);
    float* P    = (float*)w;  w += (size_t)C_N * R_N * sizeof(float);
    float* g_ls = (float*)w;  w += (size_t)LIST_CAP * sizeof(float);
    unsigned* g_lp = (unsigned*)w; w += (size_t)LIST_CAP * sizeof(unsigned);
    unsigned* g_cnt = (unsigned*)w; w += 256;
    float* g_kth = (float*)w; w += 256;

    // NMS scratch aliases the dead `part` region (first use is after reduce_bias)
    char* a = (char*)part;
    unsigned long long* cand = (unsigned long long*)a; a += (size_t)C_N * 8 * 512 * sizeof(unsigned long long);
    float* svals = (float*)a;  a += (size_t)C_N * KPRE * sizeof(float);
    int*   sridx = (int*)a;    a += (size_t)C_N * KPRE * sizeof(int);
    float* cbox  = (float*)a;  a += (size_t)C_N * KPRE * 4 * sizeof(float);
    int*   nvalid = (int*)a;   a += 4096;
    unsigned long long* gmask = (unsigned long long*)a; a += (size_t)C_N * KPRE * 8 * sizeof(unsigned long long);

    zero_kernel<<<(R_N * C_N) / 256, 256, 0, stream>>>(out, g_cnt);
    gemm_part<<<64 * KSPLIT, 256, 0, stream>>>(x, Wc, Wd, part);
    reduce_bias<<<(R_N * NC2) / 256, 256, 0, stream>>>(part, bc, bd, cls, detT);
    row_softmax<<<R_N / 4, 256, 0, stream>>>(cls, P);
    col_softmax_mul<<<C_N, 256, 0, stream>>>(detT, P);
    chunk_sort<<<C_N * 8, 256, 0, stream>>>(P, cand);
    merge_extract<<<C_N, 256, 0, stream>>>(cand, boxes, svals, sridx, cbox, nvalid);
    iou_mask<<<C_N * 8, 256, 0, stream>>>(cbox, nvalid, gmask);
    nms_scan<<<C_N, 64, 0, stream>>>(gmask, svals, sridx, nvalid, g_ls, g_lp, g_cnt);
    kth_kernel<<<1, 256, 0, stream>>>(g_ls, g_cnt, g_kth);
    scatter_kernel<<<(LIST_CAP + 255) / 256, 256, 0, stream>>>(g_ls, g_lp, g_cnt, g_kth, out);
}

// Round 4
// 462.270 us; speedup vs baseline: 1.4787x; 1.1064x over previous
//
#include <hip/hip_runtime.h>
#include <hip/hip_bf16.h>
#include <math.h>

#define R_N 8192
#define D_K 4096
#define C_N 80
#define NC2 160          // both heads concatenated
#define KSPLIT 8
#define KSLICE (D_K / KSPLIT)   // 512
#define KPRE 512
#define TOPK 100
#define LIST_CAP (80 * 512)

typedef _Float16 f16;
typedef f16 f16x8 __attribute__((ext_vector_type(8)));
typedef float f32x4 __attribute__((ext_vector_type(4)));

__device__ __forceinline__ void async_copy16(const void* g, void* l) {
    __builtin_amdgcn_global_load_lds(
        (const __attribute__((address_space(1))) void*)g,
        (__attribute__((address_space(3))) void*)l, 16, 0, 0);
}

// ---------------------------------------------------------------------------
// zero d_out + counter
// ---------------------------------------------------------------------------
__global__ __launch_bounds__(256) void zero_kernel(float* __restrict__ out, unsigned* __restrict__ cnt) {
    int idx = blockIdx.x * 256 + threadIdx.x;
    if (idx < R_N * C_N) out[idx] = 0.0f;
    if (blockIdx.x == 0 && threadIdx.x == 0) *cnt = 0u;
}

// ---------------------------------------------------------------------------
// W pre-transpose + hi/lo f16 split: BhT/BlT[n][k], n: 0..79=Wc, 80..159=Wd.
// one block per output row n; reads are column-gathers (L2-hot, tiny input).
// ---------------------------------------------------------------------------
__global__ __launch_bounds__(256) void wt_convert(const float* __restrict__ Wc,
                                                  const float* __restrict__ Wd,
                                                  f16* __restrict__ BhT,
                                                  f16* __restrict__ BlT) {
    const int n = blockIdx.x;
    const float* src = (n < C_N) ? (Wc + n) : (Wd + (n - C_N));
    f16* dh = BhT + (size_t)n * D_K;
    f16* dl = BlT + (size_t)n * D_K;
    for (int k = threadIdx.x; k < D_K; k += 256) {
        float v = src[(size_t)k * C_N];
        f16 h = (f16)v;
        dh[k] = h;
        dl[k] = (f16)(v - (float)h);
    }
}

// ---------------------------------------------------------------------------
// fused dual GEMM via f16 split-2 MFMA (al*bh + ah*bl + ah*bh), K-split into
// fp32 partials [KSPLIT][R][160]. grid: 64 row-blocks x 8 K-slices, 4 waves.
// A staged fp32 via global_load_lds (XOR-swizzled 16B chunks), hi/lo split in
// registers. B staged via global_load_lds from pre-transposed BhT/BlT.
// mfma_f32_16x16x32_f16: A[m=lane&15][k=quad*8+j], B[k][n=lane&15],
// C/D: col=lane&15, row=quad*4+reg.
// ---------------------------------------------------------------------------
__global__ __launch_bounds__(256) void gemm_part(const float* __restrict__ x,
                                                 const f16* __restrict__ BhT,
                                                 const f16* __restrict__ BlT,
                                                 float* __restrict__ part) {
    __shared__ __align__(16) float As[128 * 32];   // [r][32k], 16B chunks XOR-swizzled
    __shared__ __align__(16) f16 Bhs[160 * 32];    // [nn][32k] contiguous
    __shared__ __align__(16) f16 Bls[160 * 32];

    const int b    = blockIdx.x;
    const int rb   = b & 63;
    const int ks   = b >> 6;
    const int row0 = rb * 128;
    const int kbase = ks * KSLICE;
    const int tid  = threadIdx.x;
    const int wv   = tid >> 6, lane = tid & 63;
    const int m    = lane & 15, quad = lane >> 4;

    f32x4 acc[2][10];
#pragma unroll
    for (int t = 0; t < 2; ++t)
#pragma unroll
        for (int n = 0; n < 10; ++n) acc[t][n] = (f32x4)(0.0f);

    for (int ch = 0; ch < KSLICE / 32; ++ch) {
        const int k0 = kbase + ch * 32;
        // ---- A DMA: 128 rows x 32 fp32 = 1024 16B-chunks, XOR swizzle ----
#pragma unroll
        for (int i = 0; i < 4; ++i) {
            int t = tid + 256 * i;
            int r = t >> 3, cs = t & 7;
            int cg = cs ^ (r & 7);
            async_copy16(x + (size_t)(row0 + r) * D_K + k0 + cg * 4,
                         (char*)As + (size_t)t * 16);
        }
        // ---- B DMA: 160 rows x 32 f16 (64B) = 640 16B-chunks, hi+lo ----
#pragma unroll
        for (int i = 0; i < 3; ++i) {
            int t = tid + 256 * i;
            if (t < 640) {
                int nn = t >> 2, cc = t & 3;
                size_t go = (size_t)nn * D_K + k0 + cc * 8;
                async_copy16(BhT + go, (char*)Bhs + (size_t)t * 16);
                async_copy16(BlT + go, (char*)Bls + (size_t)t * 16);
            }
        }
        __syncthreads();
        // ---- A fragments: read fp32, split hi/lo in registers ----
        f16x8 ah[2], al[2];
#pragma unroll
        for (int t = 0; t < 2; ++t) {
            int r = wv * 32 + t * 16 + m;
            int r7 = r & 7;
            float4 c0 = *(const float4*)&As[r * 32 + (((2 * quad) ^ r7) << 2)];
            float4 c1 = *(const float4*)&As[r * 32 + (((2 * quad + 1) ^ r7) << 2)];
            float tv[8] = {c0.x, c0.y, c0.z, c0.w, c1.x, c1.y, c1.z, c1.w};
#pragma unroll
            for (int j = 0; j < 8; ++j) {
                f16 h = (f16)tv[j];
                ah[t][j] = h;
                al[t][j] = (f16)(tv[j] - (float)h);
            }
        }
        // ---- MFMA ----
#pragma unroll
        for (int n = 0; n < 10; ++n) {
            int nn = n * 16 + m;
            f16x8 bh = *(const f16x8*)&Bhs[nn * 32 + quad * 8];
            f16x8 bl = *(const f16x8*)&Bls[nn * 32 + quad * 8];
#pragma unroll
            for (int t = 0; t < 2; ++t) {
                acc[t][n] = __builtin_amdgcn_mfma_f32_16x16x32_f16(al[t], bh, acc[t][n], 0, 0, 0);
                acc[t][n] = __builtin_amdgcn_mfma_f32_16x16x32_f16(ah[t], bl, acc[t][n], 0, 0, 0);
                acc[t][n] = __builtin_amdgcn_mfma_f32_16x16x32_f16(ah[t], bh, acc[t][n], 0, 0, 0);
            }
        }
        __syncthreads();
    }
    // ---- epilogue: scatter C/D fragments to partials ----
#pragma unroll
    for (int t = 0; t < 2; ++t) {
        int grow0 = row0 + wv * 32 + t * 16 + quad * 4;
#pragma unroll
        for (int n = 0; n < 10; ++n) {
            int gcol = n * 16 + m;
#pragma unroll
            for (int r4 = 0; r4 < 4; ++r4)
                part[((size_t)ks * R_N + grow0 + r4) * NC2 + gcol] = acc[t][n][r4];
        }
    }
}

// ---------------------------------------------------------------------------
// reduce K-split partials (pairwise tree, deterministic), add bias, route
// ---------------------------------------------------------------------------
__global__ __launch_bounds__(256) void reduce_bias(const float* __restrict__ part,
                                                   const float* __restrict__ bc,
                                                   const float* __restrict__ bd,
                                                   float* __restrict__ cls,
                                                   float* __restrict__ detT) {
    const size_t STRIDE = (size_t)R_N * NC2;
    size_t idx = (size_t)blockIdx.x * 256 + threadIdx.x;
    int row = (int)(idx / NC2), col = (int)(idx % NC2);
    float p0 = part[idx + 0 * STRIDE], p1 = part[idx + 1 * STRIDE];
    float p2 = part[idx + 2 * STRIDE], p3 = part[idx + 3 * STRIDE];
    float p4 = part[idx + 4 * STRIDE], p5 = part[idx + 5 * STRIDE];
    float p6 = part[idx + 6 * STRIDE], p7 = part[idx + 7 * STRIDE];
    float s = ((p0 + p1) + (p2 + p3)) + ((p4 + p5) + (p6 + p7));
    if (col < C_N) {
        cls[(size_t)row * C_N + col] = s + bc[col];
    } else {
        detT[(size_t)(col - C_N) * R_N + row] = s + bd[col - C_N];
    }
}

// ---------------------------------------------------------------------------
// softmax over classes (axis=1); writes result transposed into P [C][R]
// ---------------------------------------------------------------------------
__global__ __launch_bounds__(256) void row_softmax(const float* __restrict__ cls,
                                                   float* __restrict__ P) {
    int tid = threadIdx.x;
    int wave = tid >> 6, lane = tid & 63;
    int row = blockIdx.x * 4 + wave;
    float v0 = cls[(size_t)row * C_N + lane];
    float v1 = (lane < 16) ? cls[(size_t)row * C_N + 64 + lane] : -INFINITY;
    float m = fmaxf(v0, v1);
#pragma unroll
    for (int off = 32; off > 0; off >>= 1) m = fmaxf(m, __shfl_xor(m, off, 64));
    float e0 = expf(v0 - m);
    float e1 = (lane < 16) ? expf(v1 - m) : 0.0f;
    float s = e0 + e1;
#pragma unroll
    for (int off = 32; off > 0; off >>= 1) s += __shfl_xor(s, off, 64);
    P[(size_t)lane * R_N + row] = e0 / s;
    if (lane < 16) P[(size_t)(64 + lane) * R_N + row] = e1 / s;
}

// ---------------------------------------------------------------------------
// softmax over proposals (axis=0) per class, multiplied into P
// ---------------------------------------------------------------------------
__global__ __launch_bounds__(256) void col_softmax_mul(const float* __restrict__ detT,
                                                       float* __restrict__ P) {
    __shared__ float red[256];
    int c = blockIdx.x, tid = threadIdx.x;
    const float* dc = detT + (size_t)c * R_N;
    float m = -INFINITY;
    for (int r = tid; r < R_N; r += 256) m = fmaxf(m, dc[r]);
    red[tid] = m; __syncthreads();
    for (int s2 = 128; s2 > 0; s2 >>= 1) {
        if (tid < s2) red[tid] = fmaxf(red[tid], red[tid + s2]);
        __syncthreads();
    }
    m = red[0]; __syncthreads();
    float sum = 0.0f;
    for (int r = tid; r < R_N; r += 256) sum += expf(dc[r] - m);
    red[tid] = sum; __syncthreads();
    for (int s2 = 128; s2 > 0; s2 >>= 1) {
        if (tid < s2) red[tid] += red[tid + s2];
        __syncthreads();
    }
    float s = red[0];
    float* pc = P + (size_t)c * R_N;
    for (int r = tid; r < R_N; r += 256) pc[r] = pc[r] * (expf(dc[r] - m) / s);
}

// ---------------------------------------------------------------------------
// Stage A: per (class, chunk of 1024) bitonic sort of composite keys,
// emit sorted top-512. key = (score_bits << 32) | (8191 - r).
// ---------------------------------------------------------------------------
__global__ __launch_bounds__(256) void chunk_sort(const float* __restrict__ P,
                                                  unsigned long long* __restrict__ cand) {
    __shared__ unsigned long long sk[1024];
    const int c = blockIdx.x >> 3, ch = blockIdx.x & 7;
    const int tid = threadIdx.x;
    const float* pc = P + (size_t)c * R_N + ch * 1024;

    for (int i = tid; i < 1024; i += 256) {
        unsigned u = __float_as_uint(pc[i]);
        int r = ch * 1024 + i;
        sk[i] = ((unsigned long long)u << 32) | (unsigned)(8191 - r);
    }
    __syncthreads();
    for (int size = 2; size <= 1024; size <<= 1) {
        for (int stride = size >> 1; stride > 0; stride >>= 1) {
            for (int t = tid; t < 512; t += 256) {
                int i = 2 * t - (t & (stride - 1));
                int j = i + stride;
                unsigned long long a = sk[i], b = sk[j];
                bool desc = ((i & size) == 0);
                if ((a < b) == desc) { sk[i] = b; sk[j] = a; }
            }
            __syncthreads();
        }
    }
    unsigned long long* dst = cand + (size_t)blockIdx.x * 512;
    for (int i = tid; i < 512; i += 256) dst[i] = sk[i];
}

// ---------------------------------------------------------------------------
// Stage B: fold 8 sorted 512-lists into the exact class top-512.
// ---------------------------------------------------------------------------
__global__ __launch_bounds__(256) void merge_extract(const unsigned long long* __restrict__ cand,
                                                     const float* __restrict__ boxes,
                                                     float* __restrict__ svals,
                                                     int* __restrict__ sridx,
                                                     float* __restrict__ cbox,
                                                     int* __restrict__ nvalid) {
    __shared__ unsigned long long A[1024];
    const int c = blockIdx.x, tid = threadIdx.x;
    const unsigned long long* base = cand + (size_t)c * 8 * 512;

    for (int i = tid; i < 512; i += 256) A[i] = base[i];
    for (int l = 1; l < 8; ++l) {
        __syncthreads();
        for (int i = tid; i < 512; i += 256) A[512 + i] = base[l * 512 + (511 - i)];
        __syncthreads();
        for (int stride = 512; stride > 0; stride >>= 1) {
            for (int t = tid; t < 512; t += 256) {
                int i = 2 * t - (t & (stride - 1));
                int j = i + stride;
                unsigned long long a = A[i], b = A[j];
                if (a < b) { A[i] = b; A[j] = a; }
            }
            __syncthreads();
        }
    }
    __syncthreads();
    for (int i = tid; i < 512; i += 256) {
        unsigned long long k = A[i];
        float v = __uint_as_float((unsigned)(k >> 32));
        int r = 8191 - (int)(k & 0xFFFFFFFFull);
        svals[c * 512 + i] = v;
        sridx[c * 512 + i] = r;
        float b0 = boxes[r * 4 + 0], b1 = boxes[r * 4 + 1];
        float b2 = boxes[r * 4 + 2], b3 = boxes[r * 4 + 3];
        float4 cb;
        cb.x = fminf(fmaxf(b0, 0.0f), 1000.0f);
        cb.y = fminf(fmaxf(b1, 0.0f), 800.0f);
        cb.z = fminf(fmaxf(b2, 0.0f), 1000.0f);
        cb.w = fminf(fmaxf(b3, 0.0f), 800.0f);
        *(float4*)&cbox[((size_t)c * 512 + i) * 4] = cb;
        float vn = (i < 511) ? __uint_as_float((unsigned)(A[i + 1] >> 32)) : -1.0f;
        if (v > 1e-5f && !(vn > 1e-5f)) nvalid[c] = i + 1;
        if (i == 0 && !(v > 1e-5f)) nvalid[c] = 0;
    }
}

// ---------------------------------------------------------------------------
// Stage C: suppression bitmask to global. grid = 80*8: (class, word w).
// ---------------------------------------------------------------------------
__global__ __launch_bounds__(256) void iou_mask(const float* __restrict__ cbox,
                                                const int* __restrict__ nvalid,
                                                unsigned long long* __restrict__ gmask) {
    __shared__ float sx1[512], sy1[512], sx2[512], sy2[512], sar[512];
    const int c = blockIdx.x >> 3, w = blockIdx.x & 7;
    const int tid = threadIdx.x;
    const int nv = nvalid[c];

    for (int i = tid; i < 512; i += 256) {
        float4 b = *(const float4*)&cbox[((size_t)c * 512 + i) * 4];
        sx1[i] = b.x; sy1[i] = b.y; sx2[i] = b.z; sy2[i] = b.w;
        sar[i] = (b.z - b.x) * (b.w - b.y);
    }
    __syncthreads();
    for (int i = tid; i < 512; i += 256) {
        unsigned long long bits = 0ull;
        if (i < nv && w <= (i >> 6)) {
            float xi1 = sx1[i], yi1 = sy1[i], xi2 = sx2[i], yi2 = sy2[i], ai = sar[i];
#pragma unroll 8
            for (int j2 = 0; j2 < 64; ++j2) {
                int j = (w << 6) + j2;
                float xx1 = fmaxf(xi1, sx1[j]);
                float yy1 = fmaxf(yi1, sy1[j]);
                float xx2 = fminf(xi2, sx2[j]);
                float yy2 = fminf(yi2, sy2[j]);
                float ww = fmaxf(xx2 - xx1, 0.0f);
                float hh = fmaxf(yy2 - yy1, 0.0f);
                float inter = ww * hh;
                float iou = inter / (ai + sar[j] - inter + 1e-9f);
                if (iou > 0.5f) bits |= (1ull << j2);
            }
        }
        gmask[((size_t)c * 512 + i) * 8 + w] = bits;
    }
}

// ---------------------------------------------------------------------------
// Stage D: greedy scan, one wave per class, prefetched LDS mask.
// ---------------------------------------------------------------------------
__global__ __launch_bounds__(64) void nms_scan(const unsigned long long* __restrict__ gmask,
                                               const float* __restrict__ svals,
                                               const int* __restrict__ sridx,
                                               const int* __restrict__ nvalid,
                                               float* __restrict__ g_ls,
                                               unsigned* __restrict__ g_lp,
                                               unsigned* __restrict__ g_cnt) {
    __shared__ unsigned long long sm[512 * 8];
    __shared__ unsigned char keepf[512];
    const int c = blockIdx.x, lane = threadIdx.x;
    const int nv = nvalid[c];
    const unsigned long long* gm = gmask + (size_t)c * 512 * 8;

    for (int t = lane; t < 4096; t += 64) sm[t] = gm[t];
    __syncthreads();

    const bool rd = (lane < 8);
    unsigned long long keptw = 0ull;
    unsigned long long pf[8];
#pragma unroll
    for (int d = 0; d < 8; ++d) pf[d] = rd ? sm[(d & 511) * 8 + lane] : 0ull;
    for (int i = 0; i < nv; ++i) {
        unsigned long long mm = pf[i & 7];
        int ip = (i + 8) & 511;
        pf[i & 7] = rd ? sm[ip * 8 + lane] : 0ull;
        int sup = __any((keptw & mm) != 0ull);
        int keep = !sup;
        if (keep && lane == (i >> 6)) keptw |= (1ull << (i & 63));
        if (lane == 0) keepf[i] = (unsigned char)keep;
    }
    __syncthreads();
    for (int i = lane; i < nv; i += 64) {
        if (keepf[i]) {
            unsigned pos = atomicAdd(g_cnt, 1u);
            g_ls[pos] = svals[c * 512 + i];
            g_lp[pos] = (unsigned)(sridx[c * 512 + i] * C_N + c);
        }
    }
}

// ---------------------------------------------------------------------------
// kth = 100th largest among kept scores (0 if fewer than 100 kept)
// ---------------------------------------------------------------------------
__global__ __launch_bounds__(256) void kth_kernel(const float* __restrict__ g_ls,
                                                  const unsigned* __restrict__ g_cnt,
                                                  float* __restrict__ g_kth) {
    __shared__ unsigned hist[256];
    __shared__ unsigned sh_prefix, sh_k;
    int tid = threadIdx.x;
    unsigned n = *g_cnt;
    if (n < (unsigned)TOPK) { if (tid == 0) *g_kth = 0.0f; return; }
    if (tid == 0) { sh_prefix = 0u; sh_k = TOPK; }
    __syncthreads();
    for (int b = 3; b >= 0; --b) {
        hist[tid] = 0;
        __syncthreads();
        unsigned pfx = sh_prefix;
        for (unsigned i = tid; i < n; i += 256) {
            unsigned u = __float_as_uint(g_ls[i]);
            bool ok = (b == 3) || ((u >> (8 * (b + 1))) == pfx);
            if (ok) atomicAdd(&hist[(u >> (8 * b)) & 255], 1u);
        }
        __syncthreads();
        if (tid == 0) {
            unsigned cum = 0, k = sh_k;
            for (unsigned d = 255;; --d) {
                unsigned c2 = cum + hist[d];
                if (c2 >= k || d == 0) { sh_k = k - cum; sh_prefix = (pfx << 8) | d; break; }
                cum = c2;
            }
        }
        __syncthreads();
    }
    if (tid == 0) *g_kth = __uint_as_float(sh_prefix);
}

// ---------------------------------------------------------------------------
// scatter kept scores >= kth into zeroed output [R, C]
// ---------------------------------------------------------------------------
__global__ __launch_bounds__(256) void scatter_kernel(const float* __restrict__ g_ls,
                                                      const unsigned* __restrict__ g_lp,
                                                      const unsigned* __restrict__ g_cnt,
                                                      const float* __restrict__ g_kth,
                                                      float* __restrict__ out) {
    unsigned idx = blockIdx.x * 256 + threadIdx.x;
    unsigned n = *g_cnt;
    float kth = *g_kth;
    if (idx < n) {
        float s = g_ls[idx];
        if (s >= kth) out[g_lp[idx]] = s;
    }
}

// ---------------------------------------------------------------------------
extern "C" void kernel_launch(void* const* d_in, const int* in_sizes, int n_in,
                              void* d_out, int out_size, void* d_ws, size_t ws_size,
                              hipStream_t stream) {
    const float* x     = (const float*)d_in[0];
    const float* Wc    = (const float*)d_in[1];
    const float* bc    = (const float*)d_in[2];
    const float* Wd    = (const float*)d_in[3];
    const float* bd    = (const float*)d_in[4];
    const float* boxes = (const float*)d_in[5];
    float* out = (float*)d_out;

    char* w = (char*)d_ws;
    float* part = (float*)w;  w += (size_t)KSPLIT * R_N * NC2 * sizeof(float);   // 41.9 MB (dead after reduce_bias)
    float* cls  = (float*)w;  w += (size_t)R_N * C_N * sizeof(float);
    float* detT = (float*)w;  w += (size_t)C_N * R_N * sizeof(float);
    float* P    = (float*)w;  w += (size_t)C_N * R_N * sizeof(float);
    float* g_ls = (float*)w;  w += (size_t)LIST_CAP * sizeof(float);
    unsigned* g_lp = (unsigned*)w; w += (size_t)LIST_CAP * sizeof(unsigned);
    unsigned* g_cnt = (unsigned*)w; w += 256;
    float* g_kth = (float*)w; w += 256;
    f16* BhT = (f16*)w; w += (size_t)NC2 * D_K * sizeof(f16);   // 1.31 MB
    f16* BlT = (f16*)w; w += (size_t)NC2 * D_K * sizeof(f16);   // 1.31 MB

    // NMS scratch aliases the dead `part` region (first use is after reduce_bias)
    char* a = (char*)part;
    unsigned long long* cand = (unsigned long long*)a; a += (size_t)C_N * 8 * 512 * sizeof(unsigned long long);
    float* svals = (float*)a;  a += (size_t)C_N * KPRE * sizeof(float);
    int*   sridx = (int*)a;    a += (size_t)C_N * KPRE * sizeof(int);
    float* cbox  = (float*)a;  a += (size_t)C_N * KPRE * 4 * sizeof(float);
    int*   nvalid = (int*)a;   a += 4096;
    unsigned long long* gmask = (unsigned long long*)a; a += (size_t)C_N * KPRE * 8 * sizeof(unsigned long long);

    zero_kernel<<<(R_N * C_N) / 256, 256, 0, stream>>>(out, g_cnt);
    wt_convert<<<NC2, 256, 0, stream>>>(Wc, Wd, BhT, BlT);
    gemm_part<<<64 * KSPLIT, 256, 0, stream>>>(x, BhT, BlT, part);
    reduce_bias<<<(R_N * NC2) / 256, 256, 0, stream>>>(part, bc, bd, cls, detT);
    row_softmax<<<R_N / 4, 256, 0, stream>>>(cls, P);
    col_softmax_mul<<<C_N, 256, 0, stream>>>(detT, P);
    chunk_sort<<<C_N * 8, 256, 0, stream>>>(P, cand);
    merge_extract<<<C_N, 256, 0, stream>>>(cand, boxes, svals, sridx, cbox, nvalid);
    iou_mask<<<C_N * 8, 256, 0, stream>>>(cbox, nvalid, gmask);
    nms_scan<<<C_N, 64, 0, stream>>>(gmask, svals, sridx, nvalid, g_ls, g_lp, g_cnt);
    kth_kernel<<<1, 256, 0, stream>>>(g_ls, g_cnt, g_kth);
    scatter_kernel<<<(LIST_CAP + 255) / 256, 256, 0, stream>>>(g_ls, g_lp, g_cnt, g_kth, out);
}

// Round 5
// 391.866 us; speedup vs baseline: 1.7443x; 1.1797x over previous
//
#include <hip/hip_runtime.h>
#include <hip/hip_bf16.h>
#include <math.h>

#define R_N 8192
#define D_K 4096
#define C_N 80
#define NC2 160          // both heads concatenated
#define KSPLIT 8
#define KSLICE (D_K / KSPLIT)   // 512
#define KPRE 512
#define TOPK 100
#define LIST_CAP (80 * 512)

typedef _Float16 f16;
typedef f16 f16x8 __attribute__((ext_vector_type(8)));
typedef float f32x4 __attribute__((ext_vector_type(4)));

__device__ __forceinline__ void async_copy16(const void* g, void* l) {
    __builtin_amdgcn_global_load_lds(
        (const __attribute__((address_space(1))) void*)g,
        (__attribute__((address_space(3))) void*)l, 16, 0, 0);
}

// ---------------------------------------------------------------------------
// zero d_out + counter
// ---------------------------------------------------------------------------
__global__ __launch_bounds__(256) void zero_kernel(float* __restrict__ out, unsigned* __restrict__ cnt) {
    int idx = blockIdx.x * 256 + threadIdx.x;
    if (idx < R_N * C_N) out[idx] = 0.0f;
    if (blockIdx.x == 0 && threadIdx.x == 0) *cnt = 0u;
}

// ---------------------------------------------------------------------------
// W pre-transpose + hi/lo f16 split: BhT/BlT[n][k], n: 0..79=Wc, 80..159=Wd.
// ---------------------------------------------------------------------------
__global__ __launch_bounds__(256) void wt_convert(const float* __restrict__ Wc,
                                                  const float* __restrict__ Wd,
                                                  f16* __restrict__ BhT,
                                                  f16* __restrict__ BlT) {
    const int n = blockIdx.x;
    const float* src = (n < C_N) ? (Wc + n) : (Wd + (n - C_N));
    f16* dh = BhT + (size_t)n * D_K;
    f16* dl = BlT + (size_t)n * D_K;
    for (int k = threadIdx.x; k < D_K; k += 256) {
        float v = src[(size_t)k * C_N];
        f16 h = (f16)v;
        dh[k] = h;
        dl[k] = (f16)(v - (float)h);
    }
}

// ---------------------------------------------------------------------------
// fused dual GEMM via f16 split-2 MFMA (al*bh + ah*bl + ah*bh), K-split into
// fp32 partials [KSPLIT][R][160]. grid: 64 row-blocks x 8 K-slices, 4 waves.
// ---------------------------------------------------------------------------
__global__ __launch_bounds__(256) void gemm_part(const float* __restrict__ x,
                                                 const f16* __restrict__ BhT,
                                                 const f16* __restrict__ BlT,
                                                 float* __restrict__ part) {
    __shared__ __align__(16) float As[128 * 32];   // [r][32k], 16B chunks XOR-swizzled
    __shared__ __align__(16) f16 Bhs[160 * 32];    // [nn][32k] contiguous
    __shared__ __align__(16) f16 Bls[160 * 32];

    const int b    = blockIdx.x;
    const int rb   = b & 63;
    const int ks   = b >> 6;
    const int row0 = rb * 128;
    const int kbase = ks * KSLICE;
    const int tid  = threadIdx.x;
    const int wv   = tid >> 6, lane = tid & 63;
    const int m    = lane & 15, quad = lane >> 4;

    f32x4 acc[2][10];
#pragma unroll
    for (int t = 0; t < 2; ++t)
#pragma unroll
        for (int n = 0; n < 10; ++n) acc[t][n] = (f32x4)(0.0f);

    for (int ch = 0; ch < KSLICE / 32; ++ch) {
        const int k0 = kbase + ch * 32;
        // ---- A DMA: 128 rows x 32 fp32 = 1024 16B-chunks, XOR swizzle ----
#pragma unroll
        for (int i = 0; i < 4; ++i) {
            int t = tid + 256 * i;
            int r = t >> 3, cs = t & 7;
            int cg = cs ^ (r & 7);
            async_copy16(x + (size_t)(row0 + r) * D_K + k0 + cg * 4,
                         (char*)As + (size_t)t * 16);
        }
        // ---- B DMA: 160 rows x 32 f16 (64B) = 640 16B-chunks, hi+lo ----
#pragma unroll
        for (int i = 0; i < 3; ++i) {
            int t = tid + 256 * i;
            if (t < 640) {
                int nn = t >> 2, cc = t & 3;
                size_t go = (size_t)nn * D_K + k0 + cc * 8;
                async_copy16(BhT + go, (char*)Bhs + (size_t)t * 16);
                async_copy16(BlT + go, (char*)Bls + (size_t)t * 16);
            }
        }
        __syncthreads();
        // ---- A fragments: read fp32, split hi/lo in registers ----
        f16x8 ah[2], al[2];
#pragma unroll
        for (int t = 0; t < 2; ++t) {
            int r = wv * 32 + t * 16 + m;
            int r7 = r & 7;
            float4 c0 = *(const float4*)&As[r * 32 + (((2 * quad) ^ r7) << 2)];
            float4 c1 = *(const float4*)&As[r * 32 + (((2 * quad + 1) ^ r7) << 2)];
            float tv[8] = {c0.x, c0.y, c0.z, c0.w, c1.x, c1.y, c1.z, c1.w};
#pragma unroll
            for (int j = 0; j < 8; ++j) {
                f16 h = (f16)tv[j];
                ah[t][j] = h;
                al[t][j] = (f16)(tv[j] - (float)h);
            }
        }
        // ---- MFMA ----
#pragma unroll
        for (int n = 0; n < 10; ++n) {
            int nn = n * 16 + m;
            f16x8 bh = *(const f16x8*)&Bhs[nn * 32 + quad * 8];
            f16x8 bl = *(const f16x8*)&Bls[nn * 32 + quad * 8];
#pragma unroll
            for (int t = 0; t < 2; ++t) {
                acc[t][n] = __builtin_amdgcn_mfma_f32_16x16x32_f16(al[t], bh, acc[t][n], 0, 0, 0);
                acc[t][n] = __builtin_amdgcn_mfma_f32_16x16x32_f16(ah[t], bl, acc[t][n], 0, 0, 0);
                acc[t][n] = __builtin_amdgcn_mfma_f32_16x16x32_f16(ah[t], bh, acc[t][n], 0, 0, 0);
            }
        }
        __syncthreads();
    }
    // ---- epilogue: scatter C/D fragments to partials ----
#pragma unroll
    for (int t = 0; t < 2; ++t) {
        int grow0 = row0 + wv * 32 + t * 16 + quad * 4;
#pragma unroll
        for (int n = 0; n < 10; ++n) {
            int gcol = n * 16 + m;
#pragma unroll
            for (int r4 = 0; r4 < 4; ++r4)
                part[((size_t)ks * R_N + grow0 + r4) * NC2 + gcol] = acc[t][n][r4];
        }
    }
}

// ---------------------------------------------------------------------------
// reduce K-split partials (pairwise tree, deterministic), add bias, route
// ---------------------------------------------------------------------------
__global__ __launch_bounds__(256) void reduce_bias(const float* __restrict__ part,
                                                   const float* __restrict__ bc,
                                                   const float* __restrict__ bd,
                                                   float* __restrict__ cls,
                                                   float* __restrict__ detT) {
    const size_t STRIDE = (size_t)R_N * NC2;
    size_t idx = (size_t)blockIdx.x * 256 + threadIdx.x;
    int row = (int)(idx / NC2), col = (int)(idx % NC2);
    float p0 = part[idx + 0 * STRIDE], p1 = part[idx + 1 * STRIDE];
    float p2 = part[idx + 2 * STRIDE], p3 = part[idx + 3 * STRIDE];
    float p4 = part[idx + 4 * STRIDE], p5 = part[idx + 5 * STRIDE];
    float p6 = part[idx + 6 * STRIDE], p7 = part[idx + 7 * STRIDE];
    float s = ((p0 + p1) + (p2 + p3)) + ((p4 + p5) + (p6 + p7));
    if (col < C_N) {
        cls[(size_t)row * C_N + col] = s + bc[col];
    } else {
        detT[(size_t)(col - C_N) * R_N + row] = s + bd[col - C_N];
    }
}

// ---------------------------------------------------------------------------
// softmax over classes (axis=1); writes result transposed into P [C][R]
// ---------------------------------------------------------------------------
__global__ __launch_bounds__(256) void row_softmax(const float* __restrict__ cls,
                                                   float* __restrict__ P) {
    int tid = threadIdx.x;
    int wave = tid >> 6, lane = tid & 63;
    int row = blockIdx.x * 4 + wave;
    float v0 = cls[(size_t)row * C_N + lane];
    float v1 = (lane < 16) ? cls[(size_t)row * C_N + 64 + lane] : -INFINITY;
    float m = fmaxf(v0, v1);
#pragma unroll
    for (int off = 32; off > 0; off >>= 1) m = fmaxf(m, __shfl_xor(m, off, 64));
    float e0 = expf(v0 - m);
    float e1 = (lane < 16) ? expf(v1 - m) : 0.0f;
    float s = e0 + e1;
#pragma unroll
    for (int off = 32; off > 0; off >>= 1) s += __shfl_xor(s, off, 64);
    P[(size_t)lane * R_N + row] = e0 / s;
    if (lane < 16) P[(size_t)(64 + lane) * R_N + row] = e1 / s;
}

// ---------------------------------------------------------------------------
// softmax over proposals (axis=0) per class, multiplied into P
// ---------------------------------------------------------------------------
__global__ __launch_bounds__(256) void col_softmax_mul(const float* __restrict__ detT,
                                                       float* __restrict__ P) {
    __shared__ float red[256];
    int c = blockIdx.x, tid = threadIdx.x;
    const float* dc = detT + (size_t)c * R_N;
    float m = -INFINITY;
    for (int r = tid; r < R_N; r += 256) m = fmaxf(m, dc[r]);
    red[tid] = m; __syncthreads();
    for (int s2 = 128; s2 > 0; s2 >>= 1) {
        if (tid < s2) red[tid] = fmaxf(red[tid], red[tid + s2]);
        __syncthreads();
    }
    m = red[0]; __syncthreads();
    float sum = 0.0f;
    for (int r = tid; r < R_N; r += 256) sum += expf(dc[r] - m);
    red[tid] = sum; __syncthreads();
    for (int s2 = 128; s2 > 0; s2 >>= 1) {
        if (tid < s2) red[tid] += red[tid + s2];
        __syncthreads();
    }
    float s = red[0];
    float* pc = P + (size_t)c * R_N;
    for (int r = tid; r < R_N; r += 256) pc[r] = pc[r] * (expf(dc[r] - m) / s);
}

// ---------------------------------------------------------------------------
// Stage A: per (class, chunk of 1024) bitonic sort of composite keys.
// ---------------------------------------------------------------------------
__global__ __launch_bounds__(256) void chunk_sort(const float* __restrict__ P,
                                                  unsigned long long* __restrict__ cand) {
    __shared__ unsigned long long sk[1024];
    const int c = blockIdx.x >> 3, ch = blockIdx.x & 7;
    const int tid = threadIdx.x;
    const float* pc = P + (size_t)c * R_N + ch * 1024;

    for (int i = tid; i < 1024; i += 256) {
        unsigned u = __float_as_uint(pc[i]);
        int r = ch * 1024 + i;
        sk[i] = ((unsigned long long)u << 32) | (unsigned)(8191 - r);
    }
    __syncthreads();
    for (int size = 2; size <= 1024; size <<= 1) {
        for (int stride = size >> 1; stride > 0; stride >>= 1) {
            for (int t = tid; t < 512; t += 256) {
                int i = 2 * t - (t & (stride - 1));
                int j = i + stride;
                unsigned long long a = sk[i], b = sk[j];
                bool desc = ((i & size) == 0);
                if ((a < b) == desc) { sk[i] = b; sk[j] = a; }
            }
            __syncthreads();
        }
    }
    unsigned long long* dst = cand + (size_t)blockIdx.x * 512;
    for (int i = tid; i < 512; i += 256) dst[i] = sk[i];
}

// ---------------------------------------------------------------------------
// Stage B: fold 8 sorted 512-lists into the exact class top-512.
// ---------------------------------------------------------------------------
__global__ __launch_bounds__(256) void merge_extract(const unsigned long long* __restrict__ cand,
                                                     const float* __restrict__ boxes,
                                                     float* __restrict__ svals,
                                                     int* __restrict__ sridx,
                                                     float* __restrict__ cbox,
                                                     int* __restrict__ nvalid) {
    __shared__ unsigned long long A[1024];
    const int c = blockIdx.x, tid = threadIdx.x;
    const unsigned long long* base = cand + (size_t)c * 8 * 512;

    for (int i = tid; i < 512; i += 256) A[i] = base[i];
    for (int l = 1; l < 8; ++l) {
        __syncthreads();
        for (int i = tid; i < 512; i += 256) A[512 + i] = base[l * 512 + (511 - i)];
        __syncthreads();
        for (int stride = 512; stride > 0; stride >>= 1) {
            for (int t = tid; t < 512; t += 256) {
                int i = 2 * t - (t & (stride - 1));
                int j = i + stride;
                unsigned long long a = A[i], b = A[j];
                if (a < b) { A[i] = b; A[j] = a; }
            }
            __syncthreads();
        }
    }
    __syncthreads();
    for (int i = tid; i < 512; i += 256) {
        unsigned long long k = A[i];
        float v = __uint_as_float((unsigned)(k >> 32));
        int r = 8191 - (int)(k & 0xFFFFFFFFull);
        svals[c * 512 + i] = v;
        sridx[c * 512 + i] = r;
        float b0 = boxes[r * 4 + 0], b1 = boxes[r * 4 + 1];
        float b2 = boxes[r * 4 + 2], b3 = boxes[r * 4 + 3];
        float4 cb;
        cb.x = fminf(fmaxf(b0, 0.0f), 1000.0f);
        cb.y = fminf(fmaxf(b1, 0.0f), 800.0f);
        cb.z = fminf(fmaxf(b2, 0.0f), 1000.0f);
        cb.w = fminf(fmaxf(b3, 0.0f), 800.0f);
        *(float4*)&cbox[((size_t)c * 512 + i) * 4] = cb;
        float vn = (i < 511) ? __uint_as_float((unsigned)(A[i + 1] >> 32)) : -1.0f;
        if (v > 1e-5f && !(vn > 1e-5f)) nvalid[c] = i + 1;
        if (i == 0 && !(v > 1e-5f)) nvalid[c] = 0;
    }
}

// ---------------------------------------------------------------------------
// Stage C: suppression bitmask to global. grid = 80*8: (class, word w).
// ---------------------------------------------------------------------------
__global__ __launch_bounds__(256) void iou_mask(const float* __restrict__ cbox,
                                                const int* __restrict__ nvalid,
                                                unsigned long long* __restrict__ gmask) {
    __shared__ float sx1[512], sy1[512], sx2[512], sy2[512], sar[512];
    const int c = blockIdx.x >> 3, w = blockIdx.x & 7;
    const int tid = threadIdx.x;
    const int nv = nvalid[c];

    for (int i = tid; i < 512; i += 256) {
        float4 b = *(const float4*)&cbox[((size_t)c * 512 + i) * 4];
        sx1[i] = b.x; sy1[i] = b.y; sx2[i] = b.z; sy2[i] = b.w;
        sar[i] = (b.z - b.x) * (b.w - b.y);
    }
    __syncthreads();
    for (int i = tid; i < 512; i += 256) {
        unsigned long long bits = 0ull;
        if (i < nv && w <= (i >> 6)) {
            float xi1 = sx1[i], yi1 = sy1[i], xi2 = sx2[i], yi2 = sy2[i], ai = sar[i];
#pragma unroll 8
            for (int j2 = 0; j2 < 64; ++j2) {
                int j = (w << 6) + j2;
                float xx1 = fmaxf(xi1, sx1[j]);
                float yy1 = fmaxf(yi1, sy1[j]);
                float xx2 = fminf(xi2, sx2[j]);
                float yy2 = fminf(yi2, sy2[j]);
                float ww = fmaxf(xx2 - xx1, 0.0f);
                float hh = fmaxf(yy2 - yy1, 0.0f);
                float inter = ww * hh;
                float iou = inter / (ai + sar[j] - inter + 1e-9f);
                if (iou > 0.5f) bits |= (1ull << j2);
            }
        }
        gmask[((size_t)c * 512 + i) * 8 + w] = bits;
    }
}

// ---------------------------------------------------------------------------
// Stage D: greedy scan, one wave per class, prefetched LDS mask.
// Also compacts the first 100 kept scores (desc) into k100[c][100], 0-padded.
// ---------------------------------------------------------------------------
__global__ __launch_bounds__(64) void nms_scan(const unsigned long long* __restrict__ gmask,
                                               const float* __restrict__ svals,
                                               const int* __restrict__ sridx,
                                               const int* __restrict__ nvalid,
                                               float* __restrict__ g_ls,
                                               unsigned* __restrict__ g_lp,
                                               unsigned* __restrict__ g_cnt,
                                               float* __restrict__ k100) {
    __shared__ unsigned long long sm[512 * 8];
    __shared__ unsigned char keepf[512];
    const int c = blockIdx.x, lane = threadIdx.x;
    const int nv = nvalid[c];
    const unsigned long long* gm = gmask + (size_t)c * 512 * 8;

    for (int t = lane; t < 4096; t += 64) sm[t] = gm[t];
    __syncthreads();

    const bool rd = (lane < 8);
    unsigned long long keptw = 0ull;
    unsigned long long pf[8];
#pragma unroll
    for (int d = 0; d < 8; ++d) pf[d] = rd ? sm[(d & 511) * 8 + lane] : 0ull;
    for (int i = 0; i < nv; ++i) {
        unsigned long long mm = pf[i & 7];
        int ip = (i + 8) & 511;
        pf[i & 7] = rd ? sm[ip * 8 + lane] : 0ull;
        int sup = __any((keptw & mm) != 0ull);
        int keep = !sup;
        if (keep && lane == (i >> 6)) keptw |= (1ull << (i & 63));
        if (lane == 0) keepf[i] = (unsigned char)keep;
    }
    __syncthreads();
    for (int i = lane; i < nv; i += 64) {
        if (keepf[i]) {
            unsigned pos = atomicAdd(g_cnt, 1u);
            g_ls[pos] = svals[c * 512 + i];
            g_lp[pos] = (unsigned)(sridx[c * 512 + i] * C_N + c);
        }
    }
    // ---- per-class top-100 kept candidates (desc by construction), 0-pad ----
    for (int i = lane; i < 100; i += 64) k100[c * 100 + i] = 0.0f;
    unsigned base = 0;
    for (int ch2 = 0; ch2 < 8 && (int)base < 100; ++ch2) {
        int i = ch2 * 64 + lane;
        bool kk = (i < nv) && (keepf[i] != 0);
        unsigned long long mb = __ballot(kk);
        unsigned pre = (unsigned)__popcll(mb & ((1ull << lane) - 1ull));
        if (kk && base + pre < 100)
            k100[c * 100 + base + pre] = svals[c * 512 + i];
        base += (unsigned)__popcll(mb);
    }
}

// ---------------------------------------------------------------------------
// kth = 100th largest over k100 candidates (registers + value binary search,
// no atomics). Exactly reproduces s[99]'s bit pattern; 0 if <100 kept.
// ---------------------------------------------------------------------------
__global__ __launch_bounds__(256) void kth_kernel(const float* __restrict__ k100,
                                                  float* __restrict__ g_kth) {
    __shared__ unsigned red[4];
    __shared__ unsigned s_total;
    const int tid = threadIdx.x;
    const int wv = tid >> 6, lane = tid & 63;
    unsigned v[32];
#pragma unroll
    for (int j = 0; j < 32; ++j) {
        int idx = j * 256 + tid;
        v[j] = (idx < C_N * 100) ? __float_as_uint(k100[idx]) : 0u;
    }
    unsigned lo = 0u, hi = 0x7FFFFFFFu;
    while (lo < hi) {
        unsigned mid = lo + (hi - lo + 1) / 2;
        unsigned cnt = 0;
#pragma unroll
        for (int j = 0; j < 32; ++j) cnt += (v[j] >= mid) ? 1u : 0u;
#pragma unroll
        for (int off = 32; off > 0; off >>= 1) cnt += __shfl_down(cnt, off, 64);
        if (lane == 0) red[wv] = cnt;
        __syncthreads();
        if (tid == 0) s_total = red[0] + red[1] + red[2] + red[3];
        __syncthreads();
        unsigned total = s_total;
        if (total >= (unsigned)TOPK) lo = mid; else hi = mid - 1;
    }
    if (tid == 0) *g_kth = __uint_as_float(lo);
}

// ---------------------------------------------------------------------------
// scatter kept scores >= kth into zeroed output [R, C]
// ---------------------------------------------------------------------------
__global__ __launch_bounds__(256) void scatter_kernel(const float* __restrict__ g_ls,
                                                      const unsigned* __restrict__ g_lp,
                                                      const unsigned* __restrict__ g_cnt,
                                                      const float* __restrict__ g_kth,
                                                      float* __restrict__ out) {
    unsigned idx = blockIdx.x * 256 + threadIdx.x;
    unsigned n = *g_cnt;
    float kth = *g_kth;
    if (idx < n) {
        float s = g_ls[idx];
        if (s >= kth) out[g_lp[idx]] = s;
    }
}

// ---------------------------------------------------------------------------
extern "C" void kernel_launch(void* const* d_in, const int* in_sizes, int n_in,
                              void* d_out, int out_size, void* d_ws, size_t ws_size,
                              hipStream_t stream) {
    const float* x     = (const float*)d_in[0];
    const float* Wc    = (const float*)d_in[1];
    const float* bc    = (const float*)d_in[2];
    const float* Wd    = (const float*)d_in[3];
    const float* bd    = (const float*)d_in[4];
    const float* boxes = (const float*)d_in[5];
    float* out = (float*)d_out;

    char* w = (char*)d_ws;
    float* part = (float*)w;  w += (size_t)KSPLIT * R_N * NC2 * sizeof(float);   // 41.9 MB (dead after reduce_bias)
    float* cls  = (float*)w;  w += (size_t)R_N * C_N * sizeof(float);
    float* detT = (float*)w;  w += (size_t)C_N * R_N * sizeof(float);
    float* P    = (float*)w;  w += (size_t)C_N * R_N * sizeof(float);
    float* g_ls = (float*)w;  w += (size_t)LIST_CAP * sizeof(float);
    unsigned* g_lp = (unsigned*)w; w += (size_t)LIST_CAP * sizeof(unsigned);
    unsigned* g_cnt = (unsigned*)w; w += 256;
    float* g_kth = (float*)w; w += 256;
    f16* BhT = (f16*)w; w += (size_t)NC2 * D_K * sizeof(f16);   // 1.31 MB
    f16* BlT = (f16*)w; w += (size_t)NC2 * D_K * sizeof(f16);   // 1.31 MB
    float* k100 = (float*)w; w += (size_t)C_N * 100 * sizeof(float);

    // NMS scratch aliases the dead `part` region (first use is after reduce_bias)
    char* a = (char*)part;
    unsigned long long* cand = (unsigned long long*)a; a += (size_t)C_N * 8 * 512 * sizeof(unsigned long long);
    float* svals = (float*)a;  a += (size_t)C_N * KPRE * sizeof(float);
    int*   sridx = (int*)a;    a += (size_t)C_N * KPRE * sizeof(int);
    float* cbox  = (float*)a;  a += (size_t)C_N * KPRE * 4 * sizeof(float);
    int*   nvalid = (int*)a;   a += 4096;
    unsigned long long* gmask = (unsigned long long*)a; a += (size_t)C_N * KPRE * 8 * sizeof(unsigned long long);

    zero_kernel<<<(R_N * C_N) / 256, 256, 0, stream>>>(out, g_cnt);
    wt_convert<<<NC2, 256, 0, stream>>>(Wc, Wd, BhT, BlT);
    gemm_part<<<64 * KSPLIT, 256, 0, stream>>>(x, BhT, BlT, part);
    reduce_bias<<<(R_N * NC2) / 256, 256, 0, stream>>>(part, bc, bd, cls, detT);
    row_softmax<<<R_N / 4, 256, 0, stream>>>(cls, P);
    col_softmax_mul<<<C_N, 256, 0, stream>>>(detT, P);
    chunk_sort<<<C_N * 8, 256, 0, stream>>>(P, cand);
    merge_extract<<<C_N, 256, 0, stream>>>(cand, boxes, svals, sridx, cbox, nvalid);
    iou_mask<<<C_N * 8, 256, 0, stream>>>(cbox, nvalid, gmask);
    nms_scan<<<C_N, 64, 0, stream>>>(gmask, svals, sridx, nvalid, g_ls, g_lp, g_cnt, k100);
    kth_kernel<<<1, 256, 0, stream>>>(k100, g_kth);
    scatter_kernel<<<(LIST_CAP + 255) / 256, 256, 0, stream>>>(g_ls, g_lp, g_cnt, g_kth, out);
}